// Round 12
// baseline (215.092 us; speedup 1.0000x reference)
//
#include <hip/hip_runtime.h>
#include <cstdint>

#define LVAL 4096
#define K1 1152
#define NT1 18
#define CCH 128
#define HH 128
#define WW 128
#define SSCALE 10.0f
#define NUPAD 2048
#define NACTPAD 512
#define PADPIX 4356          // 66*66
#define PIMG 557568          // 66*66*128 fp16 per image

typedef __attribute__((ext_vector_type(8))) short short8;
typedef __attribute__((ext_vector_type(8))) _Float16 half8;
typedef __attribute__((ext_vector_type(4))) float f32x4;

static __device__ __forceinline__ int clampi(int v, int lo, int hi) {
    return v < lo ? lo : (v > hi ? hi : v);
}
static __device__ __forceinline__ unsigned short f2h(float x) {
    union { _Float16 h; unsigned short u; } c; c.h = (_Float16)x; return c.u;
}
static __device__ __forceinline__ float h2f(unsigned short u) {
    union { _Float16 h; unsigned short u; } c; c.u = u; return (float)c.h;
}

// ---- downsample + transpose + fp16 straight into padded interiors ----
__global__ __launch_bounds__(256) void dst_kernel(const float* __restrict__ f,
        const float* __restrict__ b, unsigned short* __restrict__ fpad4,
        unsigned short* __restrict__ bpad4) {
    __shared__ float t[32][65];
    int h = blockIdx.x;          // 0..63
    int cg = blockIdx.y;         // 0..3
    int za = blockIdx.z;
    int img = za >> 1, arr = za & 1;
    const float* src = (arr ? b : f) + (size_t)img * CCH * HH * WW;
    unsigned short* dst = (arr ? bpad4 : fpad4) + (size_t)img * PIMG;
    int tid = threadIdx.x;
    int w = tid & 63, csub = tid >> 6;
    #pragma unroll
    for (int cc = 0; cc < 8; ++cc) {
        int cl = csub * 8 + cc;
        int ch = cg * 32 + cl;
        t[cl][w] = src[(size_t)ch * (HH * WW) + (2 * h) * WW + (2 * w)];
    }
    __syncthreads();
    int c = tid & 31, pr = tid >> 5;
    #pragma unroll
    for (int pp = 0; pp < 8; ++pp) {
        int w2 = pr * 8 + pp;
        dst[((size_t)(h + 1) * 66 + (w2 + 1)) * 128 + cg * 32 + c] = f2h(t[c][w2]);
    }
}

// ---- merged: Q norms (blocks <1024) + border fill (blocks >=1024) ----
__global__ __launch_bounds__(256) void qk_border_kernel(unsigned short* __restrict__ fpad4,
        unsigned short* __restrict__ bpad4, float* __restrict__ Q) {
    int img = blockIdx.y;
    int tid = threadIdx.x;
    if (blockIdx.x < 1024) {
        int lane = tid & 63, sub = tid >> 6;
        int pix = blockIdx.x * 4 + sub;
        const unsigned short* row = bpad4 + (size_t)img * PIMG
                                    + ((size_t)((pix >> 6) + 1) * 66 + (pix & 63) + 1) * 128;
        uint32_t hv = *(const uint32_t*)(row + lane * 2);
        float a = h2f((unsigned short)(hv & 0xffff));
        float b2 = h2f((unsigned short)(hv >> 16));
        float s = a * a + b2 * b2;
        for (int off = 32; off > 0; off >>= 1) s += __shfl_xor(s, off, 64);
        if (lane == 0) Q[img * 4096 + pix] = s;
    } else {
        int id = (blockIdx.x - 1024) * 256 + tid;
        if (id >= PADPIX * 16) return;
        int pix = id >> 4, cg = (id & 15) << 3;
        int hp = pix / 66, wp = pix - hp * 66;
        if (hp >= 1 && hp <= 64 && wp >= 1 && wp <= 64) return;
        unsigned short* fp = fpad4 + (size_t)img * PIMG + (size_t)pix * 128 + cg;
        #pragma unroll
        for (int cc = 0; cc < 8; ++cc) fp[cc] = 0;
        int hs = clampi(hp - 1, 0, 63), wsx = clampi(wp - 1, 0, 63);
        const unsigned short* sb = bpad4 + (size_t)img * PIMG
                                   + ((size_t)(hs + 1) * 66 + (wsx + 1)) * 128 + cg;
        unsigned short* bp = bpad4 + (size_t)img * PIMG + (size_t)pix * 128 + cg;
        #pragma unroll
        for (int cc = 0; cc < 8; ++cc) bp[cc] = sb[cc];
    }
}

// ---- 9-tap clamped sum of Q (was compact's ssl pass; identical FP order) ----
__global__ __launch_bounds__(256) void ss_kernel(const float* __restrict__ Q,
                                                 float* __restrict__ SS) {
    int img = blockIdx.y;
    const float* Qi = Q + img * 4096;
    int a = blockIdx.x * 256 + threadIdx.x;    // grid.x = 16
    int hb = a >> 6, wb = a & 63;
    float s = 0.f;
    #pragma unroll
    for (int i = 0; i < 3; ++i)
        #pragma unroll
        for (int j2 = 0; j2 < 3; ++j2) {
            int hl = clampi(hb + i - 1, 0, 63);
            int wl = clampi(wb + j2 - 1, 0, 63);
            s += Qi[hl * 64 + wl];
        }
    SS[img * 4096 + a] = s;
}

// ---- compaction: act list, union list/map, taps, compact inv-norms ----
__global__ __launch_bounds__(1024) void compact_kernel(const float* __restrict__ mask,
        const float* __restrict__ ssq, int* __restrict__ act, int* __restrict__ ulist,
        short* __restrict__ tapu, float* __restrict__ invn, int* __restrict__ hdr) {
    int img = blockIdx.x;
    const float* mk = mask + (size_t)img * HH * WW;
    const float* ssi = ssq + img * 4096;
    int* acti = act + img * NACTPAD;
    int* uli = ulist + img * NUPAD;
    short* tpi = tapu + (size_t)img * NACTPAD * 12;
    float* invi = invn + (size_t)img * NUPAD;
    int* hd = hdr + img * 4;
    int tid = threadIdx.x;
    int lane = tid & 63, wv = tid >> 6;
    __shared__ unsigned char flag[4096];
    __shared__ short umap[4096];
    __shared__ int actl[NACTPAD];
    __shared__ int wsum[16], woff[16];
    __shared__ int tot;

    int loc[4];
    int cnt = 0;
    #pragma unroll
    for (int k = 0; k < 4; ++k) {
        int a = tid * 4 + k;
        int hb = a >> 6, wb = a & 63;
        float s = 0.f;
        for (int di = -1; di <= 1; ++di)
            for (int dj = -1; dj <= 1; ++dj) {
                int hh = hb + di, w2 = wb + dj;
                if (hh >= 0 && hh < 64 && w2 >= 0 && w2 < 64)
                    s += mk[(2 * hh) * WW + 2 * w2];
            }
        loc[k] = (s == 0.f) ? 1 : 0;
        cnt += loc[k];
    }
    int pre = cnt;
    for (int off = 1; off < 64; off <<= 1) { int v = __shfl_up(pre, off, 64); if (lane >= off) pre += v; }
    if (lane == 63) wsum[wv] = pre;
    __syncthreads();
    if (tid == 0) { int a2 = 0; for (int w2 = 0; w2 < 16; ++w2) { woff[w2] = a2; a2 += wsum[w2]; } tot = a2; }
    __syncthreads();
    int base = woff[wv] + pre - cnt;
    int n_act = tot < NACTPAD ? tot : NACTPAD;
    {
        int p = base;
        #pragma unroll
        for (int k = 0; k < 4; ++k)
            if (loc[k]) { if (p < NACTPAD) { acti[p] = tid * 4 + k; actl[p] = tid * 4 + k; } p++; }
    }
    #pragma unroll
    for (int k = 0; k < 4; ++k) { flag[tid * 4 + k] = 0; umap[tid * 4 + k] = -1; }
    __syncthreads();
    for (int j = tid; j < n_act; j += 1024) {
        int a = actl[j];
        int sa = ((a & 63) << 6) + (a >> 6);
        #pragma unroll
        for (int ei = 0; ei < 3; ++ei) {
            int tbt = sa + ei - 1;
            if (tbt < 0 || tbt >= 4096) continue;
            int tb = ((tbt & 63) << 6) + (tbt >> 6);
            #pragma unroll
            for (int d = -1; d <= 1; ++d) {
                int rb = tb + d;
                if (rb >= 0 && rb < 4096) flag[rb] = 1;
            }
        }
    }
    __syncthreads();
    int cnt2 = 0;
    int loc2[4];
    #pragma unroll
    for (int k = 0; k < 4; ++k) { loc2[k] = flag[tid * 4 + k]; cnt2 += loc2[k]; }
    int pre2 = cnt2;
    for (int off = 1; off < 64; off <<= 1) { int v = __shfl_up(pre2, off, 64); if (lane >= off) pre2 += v; }
    if (lane == 63) wsum[wv] = pre2;
    __syncthreads();
    if (tid == 0) { int a2 = 0; for (int w2 = 0; w2 < 16; ++w2) { woff[w2] = a2; a2 += wsum[w2]; } tot = a2; }
    __syncthreads();
    int base2 = woff[wv] + pre2 - cnt2;
    int n_u = tot < NUPAD ? tot : NUPAD;
    {
        int p = base2;
        #pragma unroll
        for (int k = 0; k < 4; ++k)
            if (loc2[k]) { int ci = tid * 4 + k; if (p < NUPAD) { uli[p] = ci; umap[ci] = (short)p; } p++; }
    }
    __syncthreads();
    for (int j = tid; j < n_act; j += 1024) {
        int a = actl[j];
        int sa = ((a & 63) << 6) + (a >> 6);
        #pragma unroll
        for (int ei = 0; ei < 3; ++ei) {
            int tbt = sa + ei - 1;
            int ok = (tbt >= 0 && tbt < 4096);
            int tb = ok ? ((tbt & 63) << 6) + (tbt >> 6) : 0;
            #pragma unroll
            for (int d = -1; d <= 1; ++d) {
                short v = -1;
                if (ok) { int rb = tb + d; if (rb >= 0 && rb < 4096) v = umap[rb]; }
                tpi[j * 12 + ei * 3 + d + 1] = v;
            }
        }
    }
    for (int u = tid; u < NUPAD; u += 1024) invi[u] = 0.f;
    __syncthreads();
    for (int ci = tid; ci < 4096; ci += 1024) {
        if (flag[ci]) {
            int u = umap[ci];
            if (u >= 0) invi[u] = 1.f / fmaxf(sqrtf(ssi[ci]), 1e-4f);
        }
    }
    if (tid == 0) { hd[0] = n_act; hd[1] = n_u; }
}

// ---- BGT_c[k2][j] (compact columns, fp16), k2 = q*128+ch; grid.y = img ----
__global__ void prep_bgtc_kernel(const float* __restrict__ b, const int* __restrict__ act,
                                 const int* __restrict__ hdr, unsigned short* __restrict__ BGTc4) {
    int gimg = blockIdx.y;
    const float* bi = b + (size_t)gimg * CCH * HH * WW;
    int idx = blockIdx.x * 256 + threadIdx.x;
    int k2 = idx >> 9, j = idx & 511;
    int n_act = hdr[gimg * 4];
    unsigned short v = 0;
    if (j < n_act) {
        int a = act[gimg * NACTPAD + j];
        int ch = k2 & 127, q = k2 >> 7;
        int i = q / 3, jj = q - i * 3;
        int y = clampi(2 * (a >> 6) + i - 1, 0, 127);
        int x = clampi(2 * (a & 63) + jj - 1, 0, 127);
        v = f2h(bi[(size_t)ch * (HH * WW) + y * WW + x]);
    }
    BGTc4[(size_t)gimg * K1 * NACTPAD + idx] = v;
}

// ---------- GEMM1: 256x256 tile, BK=64, 8 waves, 8-phase counted-vmcnt, fp16 ----------
// (R1-proven form, 78 us. Structural variants all regressed: R2 32x32-MFMA
//  (bank conflicts), R4 BK=32/2-block (82), R5 128x256 (92). FROZEN.)
#define BAR() __builtin_amdgcn_s_barrier()
#define WAITV6() asm volatile("s_waitcnt vmcnt(6)" ::: "memory")
#define WAITV0() asm volatile("s_waitcnt vmcnt(0)" ::: "memory")

// tile t in [0,18): K-chunk t*64 -> shift q = t>>1, half = t&1 (same for A and B)
#define STAGEX(tt, h) do {                                                              \
    int t_ = (tt);                                                                      \
    if (t_ < NT1) {                                                                     \
        const int isB_ = ((h) == 1 || (h) == 2);                                        \
        const int hi_ = ((h) >= 2) ? 1 : 0;                                             \
        int q_ = t_ >> 1;                                                               \
        int qi_ = (q_ * 11) >> 5;                                                       \
        int qj_ = q_ - qi_ * 3;                                                         \
        int toff_ = ((qi_ * 66 + qj_) << 7) + ((t_ & 1) << 6);                          \
        _Pragma("unroll")                                                               \
        for (int r_ = 0; r_ < 2; ++r_) {                                                \
            int sl_ = hi_ * 2 + r_;                                                     \
            const unsigned short* g_ = (isB_ ? bR[sl_] : aR[sl_]) + toff_;              \
            unsigned short* l_ = lds + (isB_ ? 32768 : 0) + ((t_ & 1) << 14)            \
                                 + ((hi_ * 128 + r_ * 64 + swb) << 6);                  \
            __builtin_amdgcn_global_load_lds((const uint32_t*)(const void*)g_,          \
                                             (uint32_t*)(void*)l_, 16, 0, 0);           \
        }                                                                               \
    } } while (0)

#define LDA4(dst, cur, ah) do {                                                         \
    _Pragma("unroll")                                                                   \
    for (int f_ = 0; f_ < 4; ++f_)                                                      \
    { _Pragma("unroll")                                                                 \
      for (int s_ = 0; s_ < 2; ++s_) {                                                  \
        int row_ = wm * 128 + ((ah) * 4 + f_) * 16 + row16;                             \
        int cs_ = ((s_ << 2) + kgrp) ^ (row16 & 7);                                     \
        dst[f_ * 2 + s_] = *(const half8*)(lds + ((cur) << 14) + (row_ << 6) + (cs_ << 3)); \
    } } } while (0)

#define LDB2(cur, bh) do {                                                              \
    _Pragma("unroll")                                                                   \
    for (int f_ = 0; f_ < 2; ++f_)                                                      \
    { _Pragma("unroll")                                                                 \
      for (int s_ = 0; s_ < 2; ++s_) {                                                  \
        int row_ = wn * 64 + ((bh) * 2 + f_) * 16 + row16;                              \
        int cs_ = ((s_ << 2) + kgrp) ^ (row16 & 7);                                     \
        bv[(bh) * 4 + f_ * 2 + s_] = *(const half8*)(lds + 32768 + ((cur) << 14) + (row_ << 6) + (cs_ << 3)); \
    } } } while (0)

#define MFMA16(va, ai, bj) do {                                                         \
    __builtin_amdgcn_s_setprio(1);                                                      \
    _Pragma("unroll")                                                                   \
    for (int f_ = 0; f_ < 4; ++f_)                                                      \
    { _Pragma("unroll")                                                                 \
      for (int g_ = 0; g_ < 2; ++g_)                                                    \
      { _Pragma("unroll")                                                               \
        for (int s_ = 0; s_ < 2; ++s_)                                                  \
            acc[(ai) * 4 + f_][(bj) * 2 + g_] = __builtin_amdgcn_mfma_f32_16x16x32_f16( \
                va[f_ * 2 + s_], bv[(bj) * 4 + g_ * 2 + s_], acc[(ai) * 4 + f_][(bj) * 2 + g_], 0, 0, 0); \
    } } __builtin_amdgcn_s_setprio(0); } while (0)

__global__ __launch_bounds__(512, 2) void gemm1_8phase(const unsigned short* __restrict__ fpad4,
        const unsigned short* __restrict__ bpad4, unsigned short* __restrict__ Scc4,
        const int* __restrict__ ulist, const int* __restrict__ hdr,
        const float* __restrict__ invn) {
    __shared__ unsigned short lds[65536];
    const int gimg = blockIdx.y;
    const unsigned short* fpadI = fpad4 + (size_t)gimg * PIMG;
    const unsigned short* bpadI = bpad4 + (size_t)gimg * PIMG;
    unsigned short* C = Scc4 + (size_t)gimg * 4096 * NUPAD;
    const int* uli = ulist + gimg * NUPAD;
    const float* invi = invn + (size_t)gimg * NUPAD;
    const int n_u = hdr[gimg * 4 + 1];
    const int tid = threadIdx.x;
    const int lane = tid & 63;
    const int wave = tid >> 6;
    const int wm = wave >> 2, wn = wave & 3;
    const int row16 = lane & 15, kgrp = lane >> 4;
    const int srow = tid >> 3, schunk = tid & 7;
    const int swb = wave << 3;
    int bid = blockIdx.x;                       // 128 = 8 XCDs x 16
    int wgid = ((bid & 7) << 4) + (bid >> 3);
    const int bm = (wgid >> 3) << 8;            // 16 row tiles
    const int bn = (wgid & 7) << 8;             // 8 col tiles
    if (bn >= ((n_u + 255) & ~255)) return;

    const int ck8 = (schunk ^ (srow & 7)) << 3;
    const unsigned short* aR[4];
    const unsigned short* bR[4];
    #pragma unroll
    for (int i2 = 0; i2 < 4; ++i2) {
        int rowp = i2 * 64 + srow;
        int ar = bm + rowp;
        aR[i2] = fpadI + (size_t)((ar >> 6) * 66 + (ar & 63)) * 128 + ck8;
        int uu = bn + rowp;
        int brow = uli[uu < n_u ? uu : n_u - 1];
        bR[i2] = bpadI + (size_t)((brow >> 6) * 66 + (brow & 63)) * 128 + ck8;
    }

    f32x4 acc[8][4];
    #pragma unroll
    for (int i = 0; i < 8; ++i)
        #pragma unroll
        for (int j = 0; j < 4; ++j)
            acc[i][j] = (f32x4){0.f, 0.f, 0.f, 0.f};

    STAGEX(0, 1); STAGEX(0, 2); STAGEX(0, 0); STAGEX(0, 3);
    STAGEX(1, 1); STAGEX(1, 2); STAGEX(1, 0);
    WAITV6();
    BAR();

    half8 av0[8], av1[8], bv[8];
    for (int t = 0; t < NT1; ++t) {
        const int cur = t & 1;
        LDA4(av0, cur, 0);
        LDB2(cur, 0);
        LDB2(cur, 1);
        STAGEX(t + 1, 3);
        BAR();
        MFMA16(av0, 0, 0);
        LDA4(av1, cur, 1);
        BAR();
        STAGEX(t + 2, 1);
        BAR();
        MFMA16(av0, 0, 1);
        BAR();
        STAGEX(t + 2, 2);
        BAR();
        MFMA16(av1, 1, 0);
        BAR();
        STAGEX(t + 2, 0);
        BAR();
        MFMA16(av1, 1, 1);
        if (t >= NT1 - 2) { WAITV0(); } else { WAITV6(); }
        BAR();
    }

    float iv[4];
    #pragma unroll
    for (int fj = 0; fj < 4; ++fj)
        iv[fj] = invi[bn + wn * 64 + fj * 16 + row16];
    #pragma unroll
    for (int fi = 0; fi < 8; ++fi) {
        int crow = bm + wm * 128 + fi * 16 + kgrp * 4;
        #pragma unroll
        for (int fj = 0; fj < 4; ++fj) {
            int ccol = bn + wn * 64 + fj * 16 + row16;
            f32x4 v = acc[fi][fj];
            #pragma unroll
            for (int r = 0; r < 4; ++r)
                C[(size_t)(crow + r) * NUPAD + ccol] = f2h(v[r] * iv[fj]);
        }
    }
}

// ---- fused 9-tap fuse_diag + masked softmax; 16 sb per block, DMA staging ----
// R12: revisit 16-sb batching under R9's global_load_lds staging (R7's 16-sb
// regression was on the scalar-staged form with 48 live s/m/e regs). 18 phases
// serve 16 outputs (2.81 rows/sb vs 3.75 at 8-sb, -25% staged bytes); softmax
// finish runs in TWO HALVES of 8 so peak live regs ~ s[16]+m[8]+e[8].
// Accumulation order per output (ei asc via ph-j, dp asc) identical ->
// bit-identical results.
__global__ __launch_bounds__(512) void fuse_softmax_kernel(const unsigned short* __restrict__ Scc4,
        const int* __restrict__ hdr, const short* __restrict__ tapu,
        unsigned short* __restrict__ Pc4) {
    __shared__ unsigned short lrow[3][NUPAD];
    __shared__ float redm[8][8], reds[8][8];
    int gimg = blockIdx.y;
    const unsigned short* Scc = Scc4 + (size_t)gimg * 4096 * NUPAD;
    int bid = blockIdx.x;                       // [0,256)
    int sb0 = ((bid & 7) << 9) + ((bid >> 3) << 4);
    int tid = threadIdx.x;
    int lane = tid & 63, wv = tid >> 6;
    int n_act = hdr[gimg * 4];
    int n_u = hdr[gimg * 4 + 1];
    int nu_s = (n_u + 511) & ~511;              // 512-multiple: full waves only
    if (nu_s > NUPAD) nu_s = NUPAD;
    bool actv = tid < n_act;
    short tp[9];
    if (actv) {
        const short* tpp = tapu + ((size_t)gimg * NACTPAD + tid) * 12;
        #pragma unroll
        for (int t = 0; t < 9; ++t) tp[t] = tpp[t];
    }
    float s[16];
    #pragma unroll
    for (int j = 0; j < 16; ++j) s[j] = 0.f;
    for (int ph = 0; ph < 18; ++ph) {
        int tt = sb0 - 1 + ph;
        int ok = (tt >= 0 && tt < 4096);
        int ta = ok ? ((tt & 63) << 6) + (tt >> 6) : 0;
        int vmask = 0;
        #pragma unroll
        for (int dp = 0; dp < 3; ++dp) {
            int ra = ta + dp - 1;
            if (ok && ra >= 0 && ra < 4096) {
                vmask |= 1 << dp;
                const unsigned short* src = Scc + (size_t)ra * NUPAD;
                for (int u = tid * 8; u < nu_s; u += 4096)
                    __builtin_amdgcn_global_load_lds(
                        (const uint32_t*)(const void*)(src + u),
                        (uint32_t*)(void*)&lrow[dp][u], 16, 0, 0);
            }
        }
        __syncthreads();
        if (actv) {
            #pragma unroll
            for (int j = 0; j < 16; ++j) {
                int ei = ph - j;
                if (ei >= 0 && ei < 3) {
                    #pragma unroll
                    for (int dp = 0; dp < 3; ++dp) {
                        if ((vmask >> dp) & 1) {
                            int u = tp[ei * 3 + dp];
                            if (u >= 0) s[j] += h2f(lrow[dp][u]);
                        }
                    }
                }
            }
        }
        __syncthreads();
    }
    // softmax finish in two halves of 8 (register-bounded)
    for (int jh = 0; jh < 2; ++jh) {
        float m[8], e[8];
        #pragma unroll
        for (int jj = 0; jj < 8; ++jj) {
            int j = jh * 8 + jj;
            float x = actv ? SSCALE * s[j] : -3.0e38f;
            for (int off = 32; off > 0; off >>= 1) x = fmaxf(x, __shfl_xor(x, off, 64));
            if (lane == 0) redm[wv][jj] = x;
        }
        __syncthreads();
        #pragma unroll
        for (int jj = 0; jj < 8; ++jj) {
            int j = jh * 8 + jj;
            float mm = -3.0e38f;
            #pragma unroll
            for (int w2 = 0; w2 < 8; ++w2) mm = fmaxf(mm, redm[w2][jj]);
            m[jj] = fmaxf(mm, 0.f);
            e[jj] = actv ? __expf(SSCALE * s[j] - m[jj]) : 0.f;
            float sm = e[jj];
            for (int off = 32; off > 0; off >>= 1) sm += __shfl_xor(sm, off, 64);
            if (lane == 0) reds[wv][jj] = sm;
        }
        __syncthreads();
        #pragma unroll
        for (int jj = 0; jj < 8; ++jj) {
            float S = 0.f;
            #pragma unroll
            for (int w2 = 0; w2 < 8; ++w2) S += reds[w2][jj];
            float denom = S + (4096.f - (float)n_act) * __expf(-m[jj]);
            int sbj = sb0 + jh * 8 + jj;
            int b = ((sbj & 63) << 6) + (sbj >> 6);
            Pc4[(size_t)gimg * 4096 * NACTPAD + (size_t)b * NACTPAD + tid] = f2h(actv ? e[jj] / denom : 0.f);
        }
        __syncthreads();   // protect reds reuse across halves
    }
}

// ---------- GEMM2 (128x128 NT), fp16 in/out, dynamic K, 2-phase dbuf ----------
// (R3-proven form; R6's 128x256/8-wave retile regressed ~2.6 us. FROZEN.)
#define G2STAGE(bs, kk) do {                                                            \
    _Pragma("unroll")                                                                   \
    for (int r_ = 0; r_ < 4; ++r_) {                                                    \
        int row_ = (wave << 5) + (r_ << 3) + rsub;                                      \
        const unsigned short* ga_ = A + (size_t)(bm + row_) * NACTPAD + (kk) + gcol;    \
        unsigned short* la_ = lds + (bs) * 16384 + (((wave << 5) + (r_ << 3)) << 6);    \
        __builtin_amdgcn_global_load_lds((const uint32_t*)(const void*)ga_,             \
                                         (uint32_t*)(void*)la_, 16, 0, 0);              \
        const unsigned short* gb_ = B + (size_t)(bn + row_) * NACTPAD + (kk) + gcol;    \
        unsigned short* lb_ = lds + (bs) * 16384 + 8192 + (((wave << 5) + (r_ << 3)) << 6); \
        __builtin_amdgcn_global_load_lds((const uint32_t*)(const void*)gb_,             \
                                         (uint32_t*)(void*)lb_, 16, 0, 0);              \
    } } while (0)

__global__ __launch_bounds__(256) void gemm2_nt(
        const unsigned short* __restrict__ BGTc4, const unsigned short* __restrict__ Pc4,
        const int* __restrict__ hdr, unsigned short* __restrict__ OUTT4) {
    __shared__ unsigned short lds[2 * 16384];   // 64 KB: 2 bufs x (A 16KB + B 16KB)
    const int gimg = blockIdx.z;
    const unsigned short* A = BGTc4 + (size_t)gimg * K1 * NACTPAD;
    const unsigned short* B = Pc4 + (size_t)gimg * 4096 * NACTPAD;
    unsigned short* C = OUTT4 + (size_t)gimg * K1 * LVAL;
    int n_act = hdr[gimg * 4];
    int kend = (n_act + 63) & ~63;
    if (kend < 64) kend = 64;
    const int tid = threadIdx.x;
    const int wave = tid >> 6, lane = tid & 63;
    const int wm = wave >> 1, wn = wave & 1;
    const int bm = blockIdx.y << 7, bn = blockIdx.x << 7;
    const int rsub = lane >> 3, csub = lane & 7;
    const int gcol = (csub ^ rsub) << 3;
    const int row16 = lane & 15, kgrp = lane >> 4;
    const int sw = (row16 & 7) << 3;

    f32x4 acc[4][4];
    #pragma unroll
    for (int i = 0; i < 4; ++i)
        #pragma unroll
        for (int j = 0; j < 4; ++j)
            acc[i][j] = (f32x4){0.f, 0.f, 0.f, 0.f};

    G2STAGE(0, 0);
    WAITV0();
    __syncthreads();
    int nt = kend >> 6;
    for (int t = 0; t < nt; ++t) {
        const int cs = t & 1;
        if (t + 1 < nt) G2STAGE(cs ^ 1, (t + 1) << 6);
        const unsigned short* Asm = lds + cs * 16384;
        const unsigned short* Bsm = lds + cs * 16384 + 8192;
        #pragma unroll
        for (int s = 0; s < 2; ++s) {
            half8 af[4], bfr[4];
            #pragma unroll
            for (int fi = 0; fi < 4; ++fi) {
                int ar = (wm << 6) + (fi << 4) + row16;
                af[fi] = *(const half8*)(Asm + (ar << 6) + (((s << 5) + (kgrp << 3)) ^ sw));
            }
            #pragma unroll
            for (int fj = 0; fj < 4; ++fj) {
                int br = (wn << 6) + (fj << 4) + row16;
                bfr[fj] = *(const half8*)(Bsm + (br << 6) + (((s << 5) + (kgrp << 3)) ^ sw));
            }
            #pragma unroll
            for (int fi = 0; fi < 4; ++fi)
                #pragma unroll
                for (int fj = 0; fj < 4; ++fj)
                    acc[fi][fj] = __builtin_amdgcn_mfma_f32_16x16x32_f16(
                        af[fi], bfr[fj], acc[fi][fj], 0, 0, 0);
        }
        WAITV0();
        __syncthreads();
    }
    #pragma unroll
    for (int fi = 0; fi < 4; ++fi) {
        int crow = bm + (wm << 6) + (fi << 4) + (kgrp << 2);
        #pragma unroll
        for (int fj = 0; fj < 4; ++fj) {
            int ccol = bn + (wn << 6) + (fj << 4) + row16;
            f32x4 v = acc[fi][fj];
            #pragma unroll
            for (int r = 0; r < 4; ++r)
                C[(size_t)(crow + r) * LVAL + ccol] = f2h(v[r]);
        }
    }
}

// ---- transposed-conv scatter (fp16 OUTT); k2 = (i*3+j)*128 + ch ----
__global__ void scatter_kernel(const unsigned short* __restrict__ OUTT4,
                               float* __restrict__ out) {
    int gimg = blockIdx.y;
    const unsigned short* OUTT = OUTT4 + (size_t)gimg * K1 * LVAL;
    float* oi = out + (size_t)gimg * CCH * HH * WW;
    int idx = blockIdx.x * 256 + threadIdx.x;
    int x = idx & 127;
    int y = (idx >> 7) & 127;
    int ch = idx >> 14;
    int yy = y < 127 ? y : 126;
    int xx = x < 127 ? x : 126;
    int hy[2], iy[2], ny;
    if (yy & 1) { hy[0] = (yy + 1) >> 1; iy[0] = 0; hy[1] = (yy - 1) >> 1; iy[1] = 2; ny = 2; }
    else        { hy[0] = yy >> 1;       iy[0] = 1; ny = 1; }
    int wx[2], jx[2], nx;
    if (xx & 1) { wx[0] = (xx + 1) >> 1; jx[0] = 0; wx[1] = (xx - 1) >> 1; jx[1] = 2; nx = 2; }
    else        { wx[0] = xx >> 1;       jx[0] = 1; nx = 1; }
    float s = 0.f;
    for (int u = 0; u < ny; ++u)
        for (int v = 0; v < nx; ++v) {
            int k2 = (iy[u] * 3 + jx[v]) * 128 + ch;
            s += h2f(OUTT[(size_t)k2 * LVAL + (hy[u] << 6) + wx[v]]);
        }
    oi[idx] = s * 0.25f;
}

extern "C" void kernel_launch(void* const* d_in, const int* in_sizes, int n_in,
                              void* d_out, int out_size, void* d_ws, size_t ws_size,
                              hipStream_t stream) {
    const float* f = (const float*)d_in[0];
    const float* b = (const float*)d_in[1];
    const float* mask = (const float*)d_in[2];
    float* out = (float*)d_out;
    char* ws = (char*)d_ws;

    // layout (bytes)
    const size_t oQ    = 0;              // 65,536
    const size_t oACT  = 65536;          // 8,192
    const size_t oUL   = 73728;          // 32,768
    const size_t oTAP  = 106496;         // 49,152
    const size_t oHDR  = 155648;         // 1,024
    const size_t oINVN = 156672;         // 32,768
    const size_t oBGTC = 189440;         // 4,718,592
    const size_t oPC   = 4908032;        // 16,777,216
    const size_t oFPAD = 21685248;       // 4,460,544
    const size_t oBPAD = 26145792;       // 4,460,544
    const size_t oSCC  = 30606336;       // 4*4096*2048*2 = 67,108,864
    // total ~93 MB

    float* Q   = (float*)(ws + oQ);
    int*   ACT = (int*)(ws + oACT);
    int*   UL  = (int*)(ws + oUL);
    short* TAP = (short*)(ws + oTAP);
    int*   HDR = (int*)(ws + oHDR);
    float* INVN = (float*)(ws + oINVN);
    unsigned short* BGTc4 = (unsigned short*)(ws + oBGTC);
    unsigned short* Pc4   = (unsigned short*)(ws + oPC);
    unsigned short* fpad4 = (unsigned short*)(ws + oFPAD);
    unsigned short* bpad4 = (unsigned short*)(ws + oBPAD);
    unsigned short* Scc4 = (unsigned short*)(ws + oSCC);
    unsigned short* OUTT4 = (unsigned short*)(ws + oSCC);  // Scc dead after fuse
    float* SSQ = (float*)(ws + oSCC);    // 9-tap Q sums; dead before gemm1 writes Scc

    dst_kernel<<<dim3(64, 4, 8), 256, 0, stream>>>(f, b, fpad4, bpad4);
    qk_border_kernel<<<dim3(1297, 4), 256, 0, stream>>>(fpad4, bpad4, Q);
    ss_kernel<<<dim3(16, 4), 256, 0, stream>>>(Q, SSQ);
    compact_kernel<<<4, 1024, 0, stream>>>(mask, SSQ, ACT, UL, TAP, INVN, HDR);
    prep_bgtc_kernel<<<dim3(2304, 4), 256, 0, stream>>>(b, ACT, HDR, BGTc4);

    gemm1_8phase<<<dim3(128, 4), 512, 0, stream>>>(fpad4, bpad4, Scc4, UL, HDR, INVN);
    fuse_softmax_kernel<<<dim3(256, 4), 512, 0, stream>>>(Scc4, HDR, TAP, Pc4);

    gemm2_nt<<<dim3(32, 9, 4), 256, 0, stream>>>(BGTc4, Pc4, HDR, OUTT4);
    scatter_kernel<<<dim3(8192, 4), 256, 0, stream>>>(OUTT4, out);
    (void)in_sizes; (void)n_in; (void)out_size; (void)ws_size;
}

// Round 13
// 212.890 us; speedup vs baseline: 1.0103x; 1.0103x over previous
//
#include <hip/hip_runtime.h>
#include <cstdint>

#define LVAL 4096
#define K1 1152
#define NT1 18
#define CCH 128
#define HH 128
#define WW 128
#define SSCALE 10.0f
#define NUPAD 2048
#define NACTPAD 512
#define PADPIX 4356          // 66*66
#define PIMG 557568          // 66*66*128 fp16 per image

typedef __attribute__((ext_vector_type(8))) short short8;
typedef __attribute__((ext_vector_type(8))) _Float16 half8;
typedef __attribute__((ext_vector_type(4))) float f32x4;

static __device__ __forceinline__ int clampi(int v, int lo, int hi) {
    return v < lo ? lo : (v > hi ? hi : v);
}
static __device__ __forceinline__ unsigned short f2h(float x) {
    union { _Float16 h; unsigned short u; } c; c.h = (_Float16)x; return c.u;
}
static __device__ __forceinline__ float h2f(unsigned short u) {
    union { _Float16 h; unsigned short u; } c; c.u = u; return (float)c.h;
}

// ---- downsample + transpose + fp16 straight into padded interiors ----
__global__ __launch_bounds__(256) void dst_kernel(const float* __restrict__ f,
        const float* __restrict__ b, unsigned short* __restrict__ fpad4,
        unsigned short* __restrict__ bpad4) {
    __shared__ float t[32][65];
    int h = blockIdx.x;          // 0..63
    int cg = blockIdx.y;         // 0..3
    int za = blockIdx.z;
    int img = za >> 1, arr = za & 1;
    const float* src = (arr ? b : f) + (size_t)img * CCH * HH * WW;
    unsigned short* dst = (arr ? bpad4 : fpad4) + (size_t)img * PIMG;
    int tid = threadIdx.x;
    int w = tid & 63, csub = tid >> 6;
    #pragma unroll
    for (int cc = 0; cc < 8; ++cc) {
        int cl = csub * 8 + cc;
        int ch = cg * 32 + cl;
        t[cl][w] = src[(size_t)ch * (HH * WW) + (2 * h) * WW + (2 * w)];
    }
    __syncthreads();
    int c = tid & 31, pr = tid >> 5;
    #pragma unroll
    for (int pp = 0; pp < 8; ++pp) {
        int w2 = pr * 8 + pp;
        dst[((size_t)(h + 1) * 66 + (w2 + 1)) * 128 + cg * 32 + c] = f2h(t[c][w2]);
    }
}

// ---- merged: Q norms (blocks <1024) + border fill (blocks >=1024) ----
__global__ __launch_bounds__(256) void qk_border_kernel(unsigned short* __restrict__ fpad4,
        unsigned short* __restrict__ bpad4, float* __restrict__ Q) {
    int img = blockIdx.y;
    int tid = threadIdx.x;
    if (blockIdx.x < 1024) {
        int lane = tid & 63, sub = tid >> 6;
        int pix = blockIdx.x * 4 + sub;
        const unsigned short* row = bpad4 + (size_t)img * PIMG
                                    + ((size_t)((pix >> 6) + 1) * 66 + (pix & 63) + 1) * 128;
        uint32_t hv = *(const uint32_t*)(row + lane * 2);
        float a = h2f((unsigned short)(hv & 0xffff));
        float b2 = h2f((unsigned short)(hv >> 16));
        float s = a * a + b2 * b2;
        for (int off = 32; off > 0; off >>= 1) s += __shfl_xor(s, off, 64);
        if (lane == 0) Q[img * 4096 + pix] = s;
    } else {
        int id = (blockIdx.x - 1024) * 256 + tid;
        if (id >= PADPIX * 16) return;
        int pix = id >> 4, cg = (id & 15) << 3;
        int hp = pix / 66, wp = pix - hp * 66;
        if (hp >= 1 && hp <= 64 && wp >= 1 && wp <= 64) return;
        unsigned short* fp = fpad4 + (size_t)img * PIMG + (size_t)pix * 128 + cg;
        #pragma unroll
        for (int cc = 0; cc < 8; ++cc) fp[cc] = 0;
        int hs = clampi(hp - 1, 0, 63), wsx = clampi(wp - 1, 0, 63);
        const unsigned short* sb = bpad4 + (size_t)img * PIMG
                                   + ((size_t)(hs + 1) * 66 + (wsx + 1)) * 128 + cg;
        unsigned short* bp = bpad4 + (size_t)img * PIMG + (size_t)pix * 128 + cg;
        #pragma unroll
        for (int cc = 0; cc < 8; ++cc) bp[cc] = sb[cc];
    }
}

// ---- 9-tap clamped sum of Q (was compact's ssl pass; identical FP order) ----
__global__ __launch_bounds__(256) void ss_kernel(const float* __restrict__ Q,
                                                 float* __restrict__ SS) {
    int img = blockIdx.y;
    const float* Qi = Q + img * 4096;
    int a = blockIdx.x * 256 + threadIdx.x;    // grid.x = 16
    int hb = a >> 6, wb = a & 63;
    float s = 0.f;
    #pragma unroll
    for (int i = 0; i < 3; ++i)
        #pragma unroll
        for (int j2 = 0; j2 < 3; ++j2) {
            int hl = clampi(hb + i - 1, 0, 63);
            int wl = clampi(wb + j2 - 1, 0, 63);
            s += Qi[hl * 64 + wl];
        }
    SS[img * 4096 + a] = s;
}

// ---- compaction: act list, union list/map, taps, compact inv-norms ----
__global__ __launch_bounds__(1024) void compact_kernel(const float* __restrict__ mask,
        const float* __restrict__ ssq, int* __restrict__ act, int* __restrict__ ulist,
        short* __restrict__ tapu, float* __restrict__ invn, int* __restrict__ hdr) {
    int img = blockIdx.x;
    const float* mk = mask + (size_t)img * HH * WW;
    const float* ssi = ssq + img * 4096;
    int* acti = act + img * NACTPAD;
    int* uli = ulist + img * NUPAD;
    short* tpi = tapu + (size_t)img * NACTPAD * 12;
    float* invi = invn + (size_t)img * NUPAD;
    int* hd = hdr + img * 4;
    int tid = threadIdx.x;
    int lane = tid & 63, wv = tid >> 6;
    __shared__ unsigned char flag[4096];
    __shared__ short umap[4096];
    __shared__ int actl[NACTPAD];
    __shared__ int wsum[16], woff[16];
    __shared__ int tot;

    int loc[4];
    int cnt = 0;
    #pragma unroll
    for (int k = 0; k < 4; ++k) {
        int a = tid * 4 + k;
        int hb = a >> 6, wb = a & 63;
        float s = 0.f;
        for (int di = -1; di <= 1; ++di)
            for (int dj = -1; dj <= 1; ++dj) {
                int hh = hb + di, w2 = wb + dj;
                if (hh >= 0 && hh < 64 && w2 >= 0 && w2 < 64)
                    s += mk[(2 * hh) * WW + 2 * w2];
            }
        loc[k] = (s == 0.f) ? 1 : 0;
        cnt += loc[k];
    }
    int pre = cnt;
    for (int off = 1; off < 64; off <<= 1) { int v = __shfl_up(pre, off, 64); if (lane >= off) pre += v; }
    if (lane == 63) wsum[wv] = pre;
    __syncthreads();
    if (tid == 0) { int a2 = 0; for (int w2 = 0; w2 < 16; ++w2) { woff[w2] = a2; a2 += wsum[w2]; } tot = a2; }
    __syncthreads();
    int base = woff[wv] + pre - cnt;
    int n_act = tot < NACTPAD ? tot : NACTPAD;
    {
        int p = base;
        #pragma unroll
        for (int k = 0; k < 4; ++k)
            if (loc[k]) { if (p < NACTPAD) { acti[p] = tid * 4 + k; actl[p] = tid * 4 + k; } p++; }
    }
    #pragma unroll
    for (int k = 0; k < 4; ++k) { flag[tid * 4 + k] = 0; umap[tid * 4 + k] = -1; }
    __syncthreads();
    for (int j = tid; j < n_act; j += 1024) {
        int a = actl[j];
        int sa = ((a & 63) << 6) + (a >> 6);
        #pragma unroll
        for (int ei = 0; ei < 3; ++ei) {
            int tbt = sa + ei - 1;
            if (tbt < 0 || tbt >= 4096) continue;
            int tb = ((tbt & 63) << 6) + (tbt >> 6);
            #pragma unroll
            for (int d = -1; d <= 1; ++d) {
                int rb = tb + d;
                if (rb >= 0 && rb < 4096) flag[rb] = 1;
            }
        }
    }
    __syncthreads();
    int cnt2 = 0;
    int loc2[4];
    #pragma unroll
    for (int k = 0; k < 4; ++k) { loc2[k] = flag[tid * 4 + k]; cnt2 += loc2[k]; }
    int pre2 = cnt2;
    for (int off = 1; off < 64; off <<= 1) { int v = __shfl_up(pre2, off, 64); if (lane >= off) pre2 += v; }
    if (lane == 63) wsum[wv] = pre2;
    __syncthreads();
    if (tid == 0) { int a2 = 0; for (int w2 = 0; w2 < 16; ++w2) { woff[w2] = a2; a2 += wsum[w2]; } tot = a2; }
    __syncthreads();
    int base2 = woff[wv] + pre2 - cnt2;
    int n_u = tot < NUPAD ? tot : NUPAD;
    {
        int p = base2;
        #pragma unroll
        for (int k = 0; k < 4; ++k)
            if (loc2[k]) { int ci = tid * 4 + k; if (p < NUPAD) { uli[p] = ci; umap[ci] = (short)p; } p++; }
    }
    __syncthreads();
    for (int j = tid; j < n_act; j += 1024) {
        int a = actl[j];
        int sa = ((a & 63) << 6) + (a >> 6);
        #pragma unroll
        for (int ei = 0; ei < 3; ++ei) {
            int tbt = sa + ei - 1;
            int ok = (tbt >= 0 && tbt < 4096);
            int tb = ok ? ((tbt & 63) << 6) + (tbt >> 6) : 0;
            #pragma unroll
            for (int d = -1; d <= 1; ++d) {
                short v = -1;
                if (ok) { int rb = tb + d; if (rb >= 0 && rb < 4096) v = umap[rb]; }
                tpi[j * 12 + ei * 3 + d + 1] = v;
            }
        }
    }
    for (int u = tid; u < NUPAD; u += 1024) invi[u] = 0.f;
    __syncthreads();
    for (int ci = tid; ci < 4096; ci += 1024) {
        if (flag[ci]) {
            int u = umap[ci];
            if (u >= 0) invi[u] = 1.f / fmaxf(sqrtf(ssi[ci]), 1e-4f);
        }
    }
    if (tid == 0) { hd[0] = n_act; hd[1] = n_u; }
}

// ---- BGT_c[k2][j] (compact columns, fp16), k2 = q*128+ch; grid.y = img ----
__global__ void prep_bgtc_kernel(const float* __restrict__ b, const int* __restrict__ act,
                                 const int* __restrict__ hdr, unsigned short* __restrict__ BGTc4) {
    int gimg = blockIdx.y;
    const float* bi = b + (size_t)gimg * CCH * HH * WW;
    int idx = blockIdx.x * 256 + threadIdx.x;
    int k2 = idx >> 9, j = idx & 511;
    int n_act = hdr[gimg * 4];
    unsigned short v = 0;
    if (j < n_act) {
        int a = act[gimg * NACTPAD + j];
        int ch = k2 & 127, q = k2 >> 7;
        int i = q / 3, jj = q - i * 3;
        int y = clampi(2 * (a >> 6) + i - 1, 0, 127);
        int x = clampi(2 * (a & 63) + jj - 1, 0, 127);
        v = f2h(bi[(size_t)ch * (HH * WW) + y * WW + x]);
    }
    BGTc4[(size_t)gimg * K1 * NACTPAD + idx] = v;
}

// ---------- GEMM1: 256x256 tile, BK=64, 8 waves, 8-phase counted-vmcnt, fp16 ----------
// (R1-proven form, 78 us. Structural variants all regressed: R2 32x32-MFMA
//  (bank conflicts), R4 BK=32/2-block (82), R5 128x256 (92). FROZEN.)
#define BAR() __builtin_amdgcn_s_barrier()
#define WAITV6() asm volatile("s_waitcnt vmcnt(6)" ::: "memory")
#define WAITV0() asm volatile("s_waitcnt vmcnt(0)" ::: "memory")

// tile t in [0,18): K-chunk t*64 -> shift q = t>>1, half = t&1 (same for A and B)
#define STAGEX(tt, h) do {                                                              \
    int t_ = (tt);                                                                      \
    if (t_ < NT1) {                                                                     \
        const int isB_ = ((h) == 1 || (h) == 2);                                        \
        const int hi_ = ((h) >= 2) ? 1 : 0;                                             \
        int q_ = t_ >> 1;                                                               \
        int qi_ = (q_ * 11) >> 5;                                                       \
        int qj_ = q_ - qi_ * 3;                                                         \
        int toff_ = ((qi_ * 66 + qj_) << 7) + ((t_ & 1) << 6);                          \
        _Pragma("unroll")                                                               \
        for (int r_ = 0; r_ < 2; ++r_) {                                                \
            int sl_ = hi_ * 2 + r_;                                                     \
            const unsigned short* g_ = (isB_ ? bR[sl_] : aR[sl_]) + toff_;              \
            unsigned short* l_ = lds + (isB_ ? 32768 : 0) + ((t_ & 1) << 14)            \
                                 + ((hi_ * 128 + r_ * 64 + swb) << 6);                  \
            __builtin_amdgcn_global_load_lds((const uint32_t*)(const void*)g_,          \
                                             (uint32_t*)(void*)l_, 16, 0, 0);           \
        }                                                                               \
    } } while (0)

#define LDA4(dst, cur, ah) do {                                                         \
    _Pragma("unroll")                                                                   \
    for (int f_ = 0; f_ < 4; ++f_)                                                      \
    { _Pragma("unroll")                                                                 \
      for (int s_ = 0; s_ < 2; ++s_) {                                                  \
        int row_ = wm * 128 + ((ah) * 4 + f_) * 16 + row16;                             \
        int cs_ = ((s_ << 2) + kgrp) ^ (row16 & 7);                                     \
        dst[f_ * 2 + s_] = *(const half8*)(lds + ((cur) << 14) + (row_ << 6) + (cs_ << 3)); \
    } } } while (0)

#define LDB2(cur, bh) do {                                                              \
    _Pragma("unroll")                                                                   \
    for (int f_ = 0; f_ < 2; ++f_)                                                      \
    { _Pragma("unroll")                                                                 \
      for (int s_ = 0; s_ < 2; ++s_) {                                                  \
        int row_ = wn * 64 + ((bh) * 2 + f_) * 16 + row16;                              \
        int cs_ = ((s_ << 2) + kgrp) ^ (row16 & 7);                                     \
        bv[(bh) * 4 + f_ * 2 + s_] = *(const half8*)(lds + 32768 + ((cur) << 14) + (row_ << 6) + (cs_ << 3)); \
    } } } while (0)

#define MFMA16(va, ai, bj) do {                                                         \
    __builtin_amdgcn_s_setprio(1);                                                      \
    _Pragma("unroll")                                                                   \
    for (int f_ = 0; f_ < 4; ++f_)                                                      \
    { _Pragma("unroll")                                                                 \
      for (int g_ = 0; g_ < 2; ++g_)                                                    \
      { _Pragma("unroll")                                                               \
        for (int s_ = 0; s_ < 2; ++s_)                                                  \
            acc[(ai) * 4 + f_][(bj) * 2 + g_] = __builtin_amdgcn_mfma_f32_16x16x32_f16( \
                va[f_ * 2 + s_], bv[(bj) * 4 + g_ * 2 + s_], acc[(ai) * 4 + f_][(bj) * 2 + g_], 0, 0, 0); \
    } } __builtin_amdgcn_s_setprio(0); } while (0)

__global__ __launch_bounds__(512, 2) void gemm1_8phase(const unsigned short* __restrict__ fpad4,
        const unsigned short* __restrict__ bpad4, unsigned short* __restrict__ Scc4,
        const int* __restrict__ ulist, const int* __restrict__ hdr,
        const float* __restrict__ invn) {
    __shared__ unsigned short lds[65536];
    const int gimg = blockIdx.y;
    const unsigned short* fpadI = fpad4 + (size_t)gimg * PIMG;
    const unsigned short* bpadI = bpad4 + (size_t)gimg * PIMG;
    unsigned short* C = Scc4 + (size_t)gimg * 4096 * NUPAD;
    const int* uli = ulist + gimg * NUPAD;
    const float* invi = invn + (size_t)gimg * NUPAD;
    const int n_u = hdr[gimg * 4 + 1];
    const int tid = threadIdx.x;
    const int lane = tid & 63;
    const int wave = tid >> 6;
    const int wm = wave >> 2, wn = wave & 3;
    const int row16 = lane & 15, kgrp = lane >> 4;
    const int srow = tid >> 3, schunk = tid & 7;
    const int swb = wave << 3;
    int bid = blockIdx.x;                       // 128 = 8 XCDs x 16
    int wgid = ((bid & 7) << 4) + (bid >> 3);
    const int bm = (wgid >> 3) << 8;            // 16 row tiles
    const int bn = (wgid & 7) << 8;             // 8 col tiles
    if (bn >= ((n_u + 255) & ~255)) return;

    const int ck8 = (schunk ^ (srow & 7)) << 3;
    const unsigned short* aR[4];
    const unsigned short* bR[4];
    #pragma unroll
    for (int i2 = 0; i2 < 4; ++i2) {
        int rowp = i2 * 64 + srow;
        int ar = bm + rowp;
        aR[i2] = fpadI + (size_t)((ar >> 6) * 66 + (ar & 63)) * 128 + ck8;
        int uu = bn + rowp;
        int brow = uli[uu < n_u ? uu : n_u - 1];
        bR[i2] = bpadI + (size_t)((brow >> 6) * 66 + (brow & 63)) * 128 + ck8;
    }

    f32x4 acc[8][4];
    #pragma unroll
    for (int i = 0; i < 8; ++i)
        #pragma unroll
        for (int j = 0; j < 4; ++j)
            acc[i][j] = (f32x4){0.f, 0.f, 0.f, 0.f};

    STAGEX(0, 1); STAGEX(0, 2); STAGEX(0, 0); STAGEX(0, 3);
    STAGEX(1, 1); STAGEX(1, 2); STAGEX(1, 0);
    WAITV6();
    BAR();

    half8 av0[8], av1[8], bv[8];
    for (int t = 0; t < NT1; ++t) {
        const int cur = t & 1;
        LDA4(av0, cur, 0);
        LDB2(cur, 0);
        LDB2(cur, 1);
        STAGEX(t + 1, 3);
        BAR();
        MFMA16(av0, 0, 0);
        LDA4(av1, cur, 1);
        BAR();
        STAGEX(t + 2, 1);
        BAR();
        MFMA16(av0, 0, 1);
        BAR();
        STAGEX(t + 2, 2);
        BAR();
        MFMA16(av1, 1, 0);
        BAR();
        STAGEX(t + 2, 0);
        BAR();
        MFMA16(av1, 1, 1);
        if (t >= NT1 - 2) { WAITV0(); } else { WAITV6(); }
        BAR();
    }

    float iv[4];
    #pragma unroll
    for (int fj = 0; fj < 4; ++fj)
        iv[fj] = invi[bn + wn * 64 + fj * 16 + row16];
    #pragma unroll
    for (int fi = 0; fi < 8; ++fi) {
        int crow = bm + wm * 128 + fi * 16 + kgrp * 4;
        #pragma unroll
        for (int fj = 0; fj < 4; ++fj) {
            int ccol = bn + wn * 64 + fj * 16 + row16;
            f32x4 v = acc[fi][fj];
            #pragma unroll
            for (int r = 0; r < 4; ++r)
                C[(size_t)(crow + r) * NUPAD + ccol] = f2h(v[r] * iv[fj]);
        }
    }
}

// ---- fused 9-tap fuse_diag + masked softmax; 8 consecutive sb per block ----
// (R9/R11-proven optimum: 8-sb batching + global_load_lds DMA row staging,
//  213.1 us twice-validated. Batching curve mapped: 4 < 8 > 16 under both
//  scalar (R7) and DMA (R12) staging. FROZEN — final configuration.)
__global__ __launch_bounds__(512) void fuse_softmax_kernel(const unsigned short* __restrict__ Scc4,
        const int* __restrict__ hdr, const short* __restrict__ tapu,
        unsigned short* __restrict__ Pc4) {
    __shared__ unsigned short lrow[3][NUPAD];
    __shared__ float redm[8][8], reds[8][8];
    int gimg = blockIdx.y;
    const unsigned short* Scc = Scc4 + (size_t)gimg * 4096 * NUPAD;
    int bid = blockIdx.x;                       // [0,512)
    int sb0 = ((bid & 7) << 9) + ((bid >> 3) << 3);
    int tid = threadIdx.x;
    int lane = tid & 63, wv = tid >> 6;
    int n_act = hdr[gimg * 4];
    int n_u = hdr[gimg * 4 + 1];
    int nu_s = (n_u + 511) & ~511;              // 512-multiple: full waves only
    if (nu_s > NUPAD) nu_s = NUPAD;
    bool actv = tid < n_act;
    short tp[9];
    if (actv) {
        const short* tpp = tapu + ((size_t)gimg * NACTPAD + tid) * 12;
        #pragma unroll
        for (int t = 0; t < 9; ++t) tp[t] = tpp[t];
    }
    float s[8] = {0.f, 0.f, 0.f, 0.f, 0.f, 0.f, 0.f, 0.f};
    for (int ph = 0; ph < 10; ++ph) {
        int tt = sb0 - 1 + ph;
        int ok = (tt >= 0 && tt < 4096);
        int ta = ok ? ((tt & 63) << 6) + (tt >> 6) : 0;
        int vmask = 0;
        #pragma unroll
        for (int dp = 0; dp < 3; ++dp) {
            int ra = ta + dp - 1;
            if (ok && ra >= 0 && ra < 4096) {
                vmask |= 1 << dp;
                const unsigned short* src = Scc + (size_t)ra * NUPAD;
                for (int u = tid * 8; u < nu_s; u += 4096)
                    __builtin_amdgcn_global_load_lds(
                        (const uint32_t*)(const void*)(src + u),
                        (uint32_t*)(void*)&lrow[dp][u], 16, 0, 0);
            }
        }
        __syncthreads();
        if (actv) {
            #pragma unroll
            for (int j = 0; j < 8; ++j) {
                int ei = ph - j;
                if (ei >= 0 && ei < 3) {
                    #pragma unroll
                    for (int dp = 0; dp < 3; ++dp) {
                        if ((vmask >> dp) & 1) {
                            int u = tp[ei * 3 + dp];
                            if (u >= 0) s[j] += h2f(lrow[dp][u]);
                        }
                    }
                }
            }
        }
        __syncthreads();
    }
    float m[8], e[8];
    #pragma unroll
    for (int j = 0; j < 8; ++j) {
        float x = actv ? SSCALE * s[j] : -3.0e38f;
        for (int off = 32; off > 0; off >>= 1) x = fmaxf(x, __shfl_xor(x, off, 64));
        if (lane == 0) redm[wv][j] = x;
    }
    __syncthreads();
    #pragma unroll
    for (int j = 0; j < 8; ++j) {
        float mm = -3.0e38f;
        #pragma unroll
        for (int w2 = 0; w2 < 8; ++w2) mm = fmaxf(mm, redm[w2][j]);
        m[j] = fmaxf(mm, 0.f);
        e[j] = actv ? __expf(SSCALE * s[j] - m[j]) : 0.f;
        float sm = e[j];
        for (int off = 32; off > 0; off >>= 1) sm += __shfl_xor(sm, off, 64);
        if (lane == 0) reds[wv][j] = sm;
    }
    __syncthreads();
    #pragma unroll
    for (int j = 0; j < 8; ++j) {
        float S = 0.f;
        #pragma unroll
        for (int w2 = 0; w2 < 8; ++w2) S += reds[w2][j];
        float denom = S + (4096.f - (float)n_act) * __expf(-m[j]);
        int sbj = sb0 + j;
        int b = ((sbj & 63) << 6) + (sbj >> 6);
        Pc4[(size_t)gimg * 4096 * NACTPAD + (size_t)b * NACTPAD + tid] = f2h(actv ? e[j] / denom : 0.f);
    }
}

// ---------- GEMM2 (128x128 NT), fp16 in/out, dynamic K, 2-phase dbuf ----------
// (R3-proven form; R6's 128x256/8-wave retile regressed ~2.6 us. FROZEN.)
#define G2STAGE(bs, kk) do {                                                            \
    _Pragma("unroll")                                                                   \
    for (int r_ = 0; r_ < 4; ++r_) {                                                    \
        int row_ = (wave << 5) + (r_ << 3) + rsub;                                      \
        const unsigned short* ga_ = A + (size_t)(bm + row_) * NACTPAD + (kk) + gcol;    \
        unsigned short* la_ = lds + (bs) * 16384 + (((wave << 5) + (r_ << 3)) << 6);    \
        __builtin_amdgcn_global_load_lds((const uint32_t*)(const void*)ga_,             \
                                         (uint32_t*)(void*)la_, 16, 0, 0);              \
        const unsigned short* gb_ = B + (size_t)(bn + row_) * NACTPAD + (kk) + gcol;    \
        unsigned short* lb_ = lds + (bs) * 16384 + 8192 + (((wave << 5) + (r_ << 3)) << 6); \
        __builtin_amdgcn_global_load_lds((const uint32_t*)(const void*)gb_,             \
                                         (uint32_t*)(void*)lb_, 16, 0, 0);              \
    } } while (0)

__global__ __launch_bounds__(256) void gemm2_nt(
        const unsigned short* __restrict__ BGTc4, const unsigned short* __restrict__ Pc4,
        const int* __restrict__ hdr, unsigned short* __restrict__ OUTT4) {
    __shared__ unsigned short lds[2 * 16384];   // 64 KB: 2 bufs x (A 16KB + B 16KB)
    const int gimg = blockIdx.z;
    const unsigned short* A = BGTc4 + (size_t)gimg * K1 * NACTPAD;
    const unsigned short* B = Pc4 + (size_t)gimg * 4096 * NACTPAD;
    unsigned short* C = OUTT4 + (size_t)gimg * K1 * LVAL;
    int n_act = hdr[gimg * 4];
    int kend = (n_act + 63) & ~63;
    if (kend < 64) kend = 64;
    const int tid = threadIdx.x;
    const int wave = tid >> 6, lane = tid & 63;
    const int wm = wave >> 1, wn = wave & 1;
    const int bm = blockIdx.y << 7, bn = blockIdx.x << 7;
    const int rsub = lane >> 3, csub = lane & 7;
    const int gcol = (csub ^ rsub) << 3;
    const int row16 = lane & 15, kgrp = lane >> 4;
    const int sw = (row16 & 7) << 3;

    f32x4 acc[4][4];
    #pragma unroll
    for (int i = 0; i < 4; ++i)
        #pragma unroll
        for (int j = 0; j < 4; ++j)
            acc[i][j] = (f32x4){0.f, 0.f, 0.f, 0.f};

    G2STAGE(0, 0);
    WAITV0();
    __syncthreads();
    int nt = kend >> 6;
    for (int t = 0; t < nt; ++t) {
        const int cs = t & 1;
        if (t + 1 < nt) G2STAGE(cs ^ 1, (t + 1) << 6);
        const unsigned short* Asm = lds + cs * 16384;
        const unsigned short* Bsm = lds + cs * 16384 + 8192;
        #pragma unroll
        for (int s = 0; s < 2; ++s) {
            half8 af[4], bfr[4];
            #pragma unroll
            for (int fi = 0; fi < 4; ++fi) {
                int ar = (wm << 6) + (fi << 4) + row16;
                af[fi] = *(const half8*)(Asm + (ar << 6) + (((s << 5) + (kgrp << 3)) ^ sw));
            }
            #pragma unroll
            for (int fj = 0; fj < 4; ++fj) {
                int br = (wn << 6) + (fj << 4) + row16;
                bfr[fj] = *(const half8*)(Bsm + (br << 6) + (((s << 5) + (kgrp << 3)) ^ sw));
            }
            #pragma unroll
            for (int fi = 0; fi < 4; ++fi)
                #pragma unroll
                for (int fj = 0; fj < 4; ++fj)
                    acc[fi][fj] = __builtin_amdgcn_mfma_f32_16x16x32_f16(
                        af[fi], bfr[fj], acc[fi][fj], 0, 0, 0);
        }
        WAITV0();
        __syncthreads();
    }
    #pragma unroll
    for (int fi = 0; fi < 4; ++fi) {
        int crow = bm + (wm << 6) + (fi << 4) + (kgrp << 2);
        #pragma unroll
        for (int fj = 0; fj < 4; ++fj) {
            int ccol = bn + (wn << 6) + (fj << 4) + row16;
            f32x4 v = acc[fi][fj];
            #pragma unroll
            for (int r = 0; r < 4; ++r)
                C[(size_t)(crow + r) * LVAL + ccol] = f2h(v[r]);
        }
    }
}

// ---- transposed-conv scatter (fp16 OUTT); k2 = (i*3+j)*128 + ch ----
__global__ void scatter_kernel(const unsigned short* __restrict__ OUTT4,
                               float* __restrict__ out) {
    int gimg = blockIdx.y;
    const unsigned short* OUTT = OUTT4 + (size_t)gimg * K1 * LVAL;
    float* oi = out + (size_t)gimg * CCH * HH * WW;
    int idx = blockIdx.x * 256 + threadIdx.x;
    int x = idx & 127;
    int y = (idx >> 7) & 127;
    int ch = idx >> 14;
    int yy = y < 127 ? y : 126;
    int xx = x < 127 ? x : 126;
    int hy[2], iy[2], ny;
    if (yy & 1) { hy[0] = (yy + 1) >> 1; iy[0] = 0; hy[1] = (yy - 1) >> 1; iy[1] = 2; ny = 2; }
    else        { hy[0] = yy >> 1;       iy[0] = 1; ny = 1; }
    int wx[2], jx[2], nx;
    if (xx & 1) { wx[0] = (xx + 1) >> 1; jx[0] = 0; wx[1] = (xx - 1) >> 1; jx[1] = 2; nx = 2; }
    else        { wx[0] = xx >> 1;       jx[0] = 1; nx = 1; }
    float s = 0.f;
    for (int u = 0; u < ny; ++u)
        for (int v = 0; v < nx; ++v) {
            int k2 = (iy[u] * 3 + jx[v]) * 128 + ch;
            s += h2f(OUTT[(size_t)k2 * LVAL + (hy[u] << 6) + wx[v]]);
        }
    oi[idx] = s * 0.25f;
}

extern "C" void kernel_launch(void* const* d_in, const int* in_sizes, int n_in,
                              void* d_out, int out_size, void* d_ws, size_t ws_size,
                              hipStream_t stream) {
    const float* f = (const float*)d_in[0];
    const float* b = (const float*)d_in[1];
    const float* mask = (const float*)d_in[2];
    float* out = (float*)d_out;
    char* ws = (char*)d_ws;

    // layout (bytes)
    const size_t oQ    = 0;              // 65,536
    const size_t oACT  = 65536;          // 8,192
    const size_t oUL   = 73728;          // 32,768
    const size_t oTAP  = 106496;         // 49,152
    const size_t oHDR  = 155648;         // 1,024
    const size_t oINVN = 156672;         // 32,768
    const size_t oBGTC = 189440;         // 4,718,592
    const size_t oPC   = 4908032;        // 16,777,216
    const size_t oFPAD = 21685248;       // 4,460,544
    const size_t oBPAD = 26145792;       // 4,460,544
    const size_t oSCC  = 30606336;       // 4*4096*2048*2 = 67,108,864
    // total ~93 MB

    float* Q   = (float*)(ws + oQ);
    int*   ACT = (int*)(ws + oACT);
    int*   UL  = (int*)(ws + oUL);
    short* TAP = (short*)(ws + oTAP);
    int*   HDR = (int*)(ws + oHDR);
    float* INVN = (float*)(ws + oINVN);
    unsigned short* BGTc4 = (unsigned short*)(ws + oBGTC);
    unsigned short* Pc4   = (unsigned short*)(ws + oPC);
    unsigned short* fpad4 = (unsigned short*)(ws + oFPAD);
    unsigned short* bpad4 = (unsigned short*)(ws + oBPAD);
    unsigned short* Scc4 = (unsigned short*)(ws + oSCC);
    unsigned short* OUTT4 = (unsigned short*)(ws + oSCC);  // Scc dead after fuse
    float* SSQ = (float*)(ws + oSCC);    // 9-tap Q sums; dead before gemm1 writes Scc

    dst_kernel<<<dim3(64, 4, 8), 256, 0, stream>>>(f, b, fpad4, bpad4);
    qk_border_kernel<<<dim3(1297, 4), 256, 0, stream>>>(fpad4, bpad4, Q);
    ss_kernel<<<dim3(16, 4), 256, 0, stream>>>(Q, SSQ);
    compact_kernel<<<4, 1024, 0, stream>>>(mask, SSQ, ACT, UL, TAP, INVN, HDR);
    prep_bgtc_kernel<<<dim3(2304, 4), 256, 0, stream>>>(b, ACT, HDR, BGTc4);

    gemm1_8phase<<<dim3(128, 4), 512, 0, stream>>>(fpad4, bpad4, Scc4, UL, HDR, INVN);
    fuse_softmax_kernel<<<dim3(512, 4), 512, 0, stream>>>(Scc4, HDR, TAP, Pc4);

    gemm2_nt<<<dim3(32, 9, 4), 256, 0, stream>>>(BGTc4, Pc4, HDR, OUTT4);
    scatter_kernel<<<dim3(8192, 4), 256, 0, stream>>>(OUTT4, out);
    (void)in_sizes; (void)n_in; (void)out_size; (void)ws_size;
}

// Round 14
// 212.860 us; speedup vs baseline: 1.0105x; 1.0001x over previous
//
#include <hip/hip_runtime.h>
#include <cstdint>

#define LVAL 4096
#define K1 1152
#define NT1 18
#define CCH 128
#define HH 128
#define WW 128
#define SSCALE 10.0f
#define NUPAD 2048
#define NACTPAD 512
#define PADPIX 4356          // 66*66
#define PIMG 557568          // 66*66*128 fp16 per image

typedef __attribute__((ext_vector_type(8))) short short8;
typedef __attribute__((ext_vector_type(8))) _Float16 half8;
typedef __attribute__((ext_vector_type(4))) float f32x4;

static __device__ __forceinline__ int clampi(int v, int lo, int hi) {
    return v < lo ? lo : (v > hi ? hi : v);
}
static __device__ __forceinline__ unsigned short f2h(float x) {
    union { _Float16 h; unsigned short u; } c; c.h = (_Float16)x; return c.u;
}
static __device__ __forceinline__ float h2f(unsigned short u) {
    union { _Float16 h; unsigned short u; } c; c.u = u; return (float)c.h;
}

// ---- downsample + transpose + fp16 straight into padded interiors ----
__global__ __launch_bounds__(256) void dst_kernel(const float* __restrict__ f,
        const float* __restrict__ b, unsigned short* __restrict__ fpad4,
        unsigned short* __restrict__ bpad4) {
    __shared__ float t[32][65];
    int h = blockIdx.x;          // 0..63
    int cg = blockIdx.y;         // 0..3
    int za = blockIdx.z;
    int img = za >> 1, arr = za & 1;
    const float* src = (arr ? b : f) + (size_t)img * CCH * HH * WW;
    unsigned short* dst = (arr ? bpad4 : fpad4) + (size_t)img * PIMG;
    int tid = threadIdx.x;
    int w = tid & 63, csub = tid >> 6;
    #pragma unroll
    for (int cc = 0; cc < 8; ++cc) {
        int cl = csub * 8 + cc;
        int ch = cg * 32 + cl;
        t[cl][w] = src[(size_t)ch * (HH * WW) + (2 * h) * WW + (2 * w)];
    }
    __syncthreads();
    int c = tid & 31, pr = tid >> 5;
    #pragma unroll
    for (int pp = 0; pp < 8; ++pp) {
        int w2 = pr * 8 + pp;
        dst[((size_t)(h + 1) * 66 + (w2 + 1)) * 128 + cg * 32 + c] = f2h(t[c][w2]);
    }
}

// ---- merged: Q norms (blocks <1024) + border fill (blocks >=1024) ----
__global__ __launch_bounds__(256) void qk_border_kernel(unsigned short* __restrict__ fpad4,
        unsigned short* __restrict__ bpad4, float* __restrict__ Q) {
    int img = blockIdx.y;
    int tid = threadIdx.x;
    if (blockIdx.x < 1024) {
        int lane = tid & 63, sub = tid >> 6;
        int pix = blockIdx.x * 4 + sub;
        const unsigned short* row = bpad4 + (size_t)img * PIMG
                                    + ((size_t)((pix >> 6) + 1) * 66 + (pix & 63) + 1) * 128;
        uint32_t hv = *(const uint32_t*)(row + lane * 2);
        float a = h2f((unsigned short)(hv & 0xffff));
        float b2 = h2f((unsigned short)(hv >> 16));
        float s = a * a + b2 * b2;
        for (int off = 32; off > 0; off >>= 1) s += __shfl_xor(s, off, 64);
        if (lane == 0) Q[img * 4096 + pix] = s;
    } else {
        int id = (blockIdx.x - 1024) * 256 + tid;
        if (id >= PADPIX * 16) return;
        int pix = id >> 4, cg = (id & 15) << 3;
        int hp = pix / 66, wp = pix - hp * 66;
        if (hp >= 1 && hp <= 64 && wp >= 1 && wp <= 64) return;
        unsigned short* fp = fpad4 + (size_t)img * PIMG + (size_t)pix * 128 + cg;
        #pragma unroll
        for (int cc = 0; cc < 8; ++cc) fp[cc] = 0;
        int hs = clampi(hp - 1, 0, 63), wsx = clampi(wp - 1, 0, 63);
        const unsigned short* sb = bpad4 + (size_t)img * PIMG
                                   + ((size_t)(hs + 1) * 66 + (wsx + 1)) * 128 + cg;
        unsigned short* bp = bpad4 + (size_t)img * PIMG + (size_t)pix * 128 + cg;
        #pragma unroll
        for (int cc = 0; cc < 8; ++cc) bp[cc] = sb[cc];
    }
}

// ---- 9-tap clamped sum of Q (was compact's ssl pass; identical FP order) ----
__global__ __launch_bounds__(256) void ss_kernel(const float* __restrict__ Q,
                                                 float* __restrict__ SS) {
    int img = blockIdx.y;
    const float* Qi = Q + img * 4096;
    int a = blockIdx.x * 256 + threadIdx.x;    // grid.x = 16
    int hb = a >> 6, wb = a & 63;
    float s = 0.f;
    #pragma unroll
    for (int i = 0; i < 3; ++i)
        #pragma unroll
        for (int j2 = 0; j2 < 3; ++j2) {
            int hl = clampi(hb + i - 1, 0, 63);
            int wl = clampi(wb + j2 - 1, 0, 63);
            s += Qi[hl * 64 + wl];
        }
    SS[img * 4096 + a] = s;
}

// ---- compaction: act list, union list/map, taps, compact inv-norms ----
__global__ __launch_bounds__(1024) void compact_kernel(const float* __restrict__ mask,
        const float* __restrict__ ssq, int* __restrict__ act, int* __restrict__ ulist,
        short* __restrict__ tapu, float* __restrict__ invn, int* __restrict__ hdr) {
    int img = blockIdx.x;
    const float* mk = mask + (size_t)img * HH * WW;
    const float* ssi = ssq + img * 4096;
    int* acti = act + img * NACTPAD;
    int* uli = ulist + img * NUPAD;
    short* tpi = tapu + (size_t)img * NACTPAD * 12;
    float* invi = invn + (size_t)img * NUPAD;
    int* hd = hdr + img * 4;
    int tid = threadIdx.x;
    int lane = tid & 63, wv = tid >> 6;
    __shared__ unsigned char flag[4096];
    __shared__ short umap[4096];
    __shared__ int actl[NACTPAD];
    __shared__ int wsum[16], woff[16];
    __shared__ int tot;

    int loc[4];
    int cnt = 0;
    #pragma unroll
    for (int k = 0; k < 4; ++k) {
        int a = tid * 4 + k;
        int hb = a >> 6, wb = a & 63;
        float s = 0.f;
        for (int di = -1; di <= 1; ++di)
            for (int dj = -1; dj <= 1; ++dj) {
                int hh = hb + di, w2 = wb + dj;
                if (hh >= 0 && hh < 64 && w2 >= 0 && w2 < 64)
                    s += mk[(2 * hh) * WW + 2 * w2];
            }
        loc[k] = (s == 0.f) ? 1 : 0;
        cnt += loc[k];
    }
    int pre = cnt;
    for (int off = 1; off < 64; off <<= 1) { int v = __shfl_up(pre, off, 64); if (lane >= off) pre += v; }
    if (lane == 63) wsum[wv] = pre;
    __syncthreads();
    if (tid == 0) { int a2 = 0; for (int w2 = 0; w2 < 16; ++w2) { woff[w2] = a2; a2 += wsum[w2]; } tot = a2; }
    __syncthreads();
    int base = woff[wv] + pre - cnt;
    int n_act = tot < NACTPAD ? tot : NACTPAD;
    {
        int p = base;
        #pragma unroll
        for (int k = 0; k < 4; ++k)
            if (loc[k]) { if (p < NACTPAD) { acti[p] = tid * 4 + k; actl[p] = tid * 4 + k; } p++; }
    }
    #pragma unroll
    for (int k = 0; k < 4; ++k) { flag[tid * 4 + k] = 0; umap[tid * 4 + k] = -1; }
    __syncthreads();
    for (int j = tid; j < n_act; j += 1024) {
        int a = actl[j];
        int sa = ((a & 63) << 6) + (a >> 6);
        #pragma unroll
        for (int ei = 0; ei < 3; ++ei) {
            int tbt = sa + ei - 1;
            if (tbt < 0 || tbt >= 4096) continue;
            int tb = ((tbt & 63) << 6) + (tbt >> 6);
            #pragma unroll
            for (int d = -1; d <= 1; ++d) {
                int rb = tb + d;
                if (rb >= 0 && rb < 4096) flag[rb] = 1;
            }
        }
    }
    __syncthreads();
    int cnt2 = 0;
    int loc2[4];
    #pragma unroll
    for (int k = 0; k < 4; ++k) { loc2[k] = flag[tid * 4 + k]; cnt2 += loc2[k]; }
    int pre2 = cnt2;
    for (int off = 1; off < 64; off <<= 1) { int v = __shfl_up(pre2, off, 64); if (lane >= off) pre2 += v; }
    if (lane == 63) wsum[wv] = pre2;
    __syncthreads();
    if (tid == 0) { int a2 = 0; for (int w2 = 0; w2 < 16; ++w2) { woff[w2] = a2; a2 += wsum[w2]; } tot = a2; }
    __syncthreads();
    int base2 = woff[wv] + pre2 - cnt2;
    int n_u = tot < NUPAD ? tot : NUPAD;
    {
        int p = base2;
        #pragma unroll
        for (int k = 0; k < 4; ++k)
            if (loc2[k]) { int ci = tid * 4 + k; if (p < NUPAD) { uli[p] = ci; umap[ci] = (short)p; } p++; }
    }
    __syncthreads();
    for (int j = tid; j < n_act; j += 1024) {
        int a = actl[j];
        int sa = ((a & 63) << 6) + (a >> 6);
        #pragma unroll
        for (int ei = 0; ei < 3; ++ei) {
            int tbt = sa + ei - 1;
            int ok = (tbt >= 0 && tbt < 4096);
            int tb = ok ? ((tbt & 63) << 6) + (tbt >> 6) : 0;
            #pragma unroll
            for (int d = -1; d <= 1; ++d) {
                short v = -1;
                if (ok) { int rb = tb + d; if (rb >= 0 && rb < 4096) v = umap[rb]; }
                tpi[j * 12 + ei * 3 + d + 1] = v;
            }
        }
    }
    for (int u = tid; u < NUPAD; u += 1024) invi[u] = 0.f;
    __syncthreads();
    for (int ci = tid; ci < 4096; ci += 1024) {
        if (flag[ci]) {
            int u = umap[ci];
            if (u >= 0) invi[u] = 1.f / fmaxf(sqrtf(ssi[ci]), 1e-4f);
        }
    }
    if (tid == 0) { hd[0] = n_act; hd[1] = n_u; }
}

// ---- BGT_c[k2][j] (compact columns, fp16), k2 = q*128+ch; grid.y = img ----
__global__ void prep_bgtc_kernel(const float* __restrict__ b, const int* __restrict__ act,
                                 const int* __restrict__ hdr, unsigned short* __restrict__ BGTc4) {
    int gimg = blockIdx.y;
    const float* bi = b + (size_t)gimg * CCH * HH * WW;
    int idx = blockIdx.x * 256 + threadIdx.x;
    int k2 = idx >> 9, j = idx & 511;
    int n_act = hdr[gimg * 4];
    unsigned short v = 0;
    if (j < n_act) {
        int a = act[gimg * NACTPAD + j];
        int ch = k2 & 127, q = k2 >> 7;
        int i = q / 3, jj = q - i * 3;
        int y = clampi(2 * (a >> 6) + i - 1, 0, 127);
        int x = clampi(2 * (a & 63) + jj - 1, 0, 127);
        v = f2h(bi[(size_t)ch * (HH * WW) + y * WW + x]);
    }
    BGTc4[(size_t)gimg * K1 * NACTPAD + idx] = v;
}

// ---------- GEMM1: 256x256 tile, BK=64, 8 waves, 8-phase counted-vmcnt, fp16 ----------
// (R1-proven form, 78 us. Structural variants all regressed: R2 32x32-MFMA
//  (bank conflicts), R4 BK=32/2-block (82), R5 128x256 (92). FROZEN.)
#define BAR() __builtin_amdgcn_s_barrier()
#define WAITV6() asm volatile("s_waitcnt vmcnt(6)" ::: "memory")
#define WAITV0() asm volatile("s_waitcnt vmcnt(0)" ::: "memory")

// tile t in [0,18): K-chunk t*64 -> shift q = t>>1, half = t&1 (same for A and B)
#define STAGEX(tt, h) do {                                                              \
    int t_ = (tt);                                                                      \
    if (t_ < NT1) {                                                                     \
        const int isB_ = ((h) == 1 || (h) == 2);                                        \
        const int hi_ = ((h) >= 2) ? 1 : 0;                                             \
        int q_ = t_ >> 1;                                                               \
        int qi_ = (q_ * 11) >> 5;                                                       \
        int qj_ = q_ - qi_ * 3;                                                         \
        int toff_ = ((qi_ * 66 + qj_) << 7) + ((t_ & 1) << 6);                          \
        _Pragma("unroll")                                                               \
        for (int r_ = 0; r_ < 2; ++r_) {                                                \
            int sl_ = hi_ * 2 + r_;                                                     \
            const unsigned short* g_ = (isB_ ? bR[sl_] : aR[sl_]) + toff_;              \
            unsigned short* l_ = lds + (isB_ ? 32768 : 0) + ((t_ & 1) << 14)            \
                                 + ((hi_ * 128 + r_ * 64 + swb) << 6);                  \
            __builtin_amdgcn_global_load_lds((const uint32_t*)(const void*)g_,          \
                                             (uint32_t*)(void*)l_, 16, 0, 0);           \
        }                                                                               \
    } } while (0)

#define LDA4(dst, cur, ah) do {                                                         \
    _Pragma("unroll")                                                                   \
    for (int f_ = 0; f_ < 4; ++f_)                                                      \
    { _Pragma("unroll")                                                                 \
      for (int s_ = 0; s_ < 2; ++s_) {                                                  \
        int row_ = wm * 128 + ((ah) * 4 + f_) * 16 + row16;                             \
        int cs_ = ((s_ << 2) + kgrp) ^ (row16 & 7);                                     \
        dst[f_ * 2 + s_] = *(const half8*)(lds + ((cur) << 14) + (row_ << 6) + (cs_ << 3)); \
    } } } while (0)

#define LDB2(cur, bh) do {                                                              \
    _Pragma("unroll")                                                                   \
    for (int f_ = 0; f_ < 2; ++f_)                                                      \
    { _Pragma("unroll")                                                                 \
      for (int s_ = 0; s_ < 2; ++s_) {                                                  \
        int row_ = wn * 64 + ((bh) * 2 + f_) * 16 + row16;                              \
        int cs_ = ((s_ << 2) + kgrp) ^ (row16 & 7);                                     \
        bv[(bh) * 4 + f_ * 2 + s_] = *(const half8*)(lds + 32768 + ((cur) << 14) + (row_ << 6) + (cs_ << 3)); \
    } } } while (0)

#define MFMA16(va, ai, bj) do {                                                         \
    __builtin_amdgcn_s_setprio(1);                                                      \
    _Pragma("unroll")                                                                   \
    for (int f_ = 0; f_ < 4; ++f_)                                                      \
    { _Pragma("unroll")                                                                 \
      for (int g_ = 0; g_ < 2; ++g_)                                                    \
      { _Pragma("unroll")                                                               \
        for (int s_ = 0; s_ < 2; ++s_)                                                  \
            acc[(ai) * 4 + f_][(bj) * 2 + g_] = __builtin_amdgcn_mfma_f32_16x16x32_f16( \
                va[f_ * 2 + s_], bv[(bj) * 4 + g_ * 2 + s_], acc[(ai) * 4 + f_][(bj) * 2 + g_], 0, 0, 0); \
    } } __builtin_amdgcn_s_setprio(0); } while (0)

__global__ __launch_bounds__(512, 2) void gemm1_8phase(const unsigned short* __restrict__ fpad4,
        const unsigned short* __restrict__ bpad4, unsigned short* __restrict__ Scc4,
        const int* __restrict__ ulist, const int* __restrict__ hdr,
        const float* __restrict__ invn) {
    __shared__ unsigned short lds[65536];
    const int gimg = blockIdx.y;
    const unsigned short* fpadI = fpad4 + (size_t)gimg * PIMG;
    const unsigned short* bpadI = bpad4 + (size_t)gimg * PIMG;
    unsigned short* C = Scc4 + (size_t)gimg * 4096 * NUPAD;
    const int* uli = ulist + gimg * NUPAD;
    const float* invi = invn + (size_t)gimg * NUPAD;
    const int n_u = hdr[gimg * 4 + 1];
    const int tid = threadIdx.x;
    const int lane = tid & 63;
    const int wave = tid >> 6;
    const int wm = wave >> 2, wn = wave & 3;
    const int row16 = lane & 15, kgrp = lane >> 4;
    const int srow = tid >> 3, schunk = tid & 7;
    const int swb = wave << 3;
    int bid = blockIdx.x;                       // 128 = 8 XCDs x 16
    int wgid = ((bid & 7) << 4) + (bid >> 3);
    const int bm = (wgid >> 3) << 8;            // 16 row tiles
    const int bn = (wgid & 7) << 8;             // 8 col tiles
    if (bn >= ((n_u + 255) & ~255)) return;

    const int ck8 = (schunk ^ (srow & 7)) << 3;
    const unsigned short* aR[4];
    const unsigned short* bR[4];
    #pragma unroll
    for (int i2 = 0; i2 < 4; ++i2) {
        int rowp = i2 * 64 + srow;
        int ar = bm + rowp;
        aR[i2] = fpadI + (size_t)((ar >> 6) * 66 + (ar & 63)) * 128 + ck8;
        int uu = bn + rowp;
        int brow = uli[uu < n_u ? uu : n_u - 1];
        bR[i2] = bpadI + (size_t)((brow >> 6) * 66 + (brow & 63)) * 128 + ck8;
    }

    f32x4 acc[8][4];
    #pragma unroll
    for (int i = 0; i < 8; ++i)
        #pragma unroll
        for (int j = 0; j < 4; ++j)
            acc[i][j] = (f32x4){0.f, 0.f, 0.f, 0.f};

    STAGEX(0, 1); STAGEX(0, 2); STAGEX(0, 0); STAGEX(0, 3);
    STAGEX(1, 1); STAGEX(1, 2); STAGEX(1, 0);
    WAITV6();
    BAR();

    half8 av0[8], av1[8], bv[8];
    for (int t = 0; t < NT1; ++t) {
        const int cur = t & 1;
        LDA4(av0, cur, 0);
        LDB2(cur, 0);
        LDB2(cur, 1);
        STAGEX(t + 1, 3);
        BAR();
        MFMA16(av0, 0, 0);
        LDA4(av1, cur, 1);
        BAR();
        STAGEX(t + 2, 1);
        BAR();
        MFMA16(av0, 0, 1);
        BAR();
        STAGEX(t + 2, 2);
        BAR();
        MFMA16(av1, 1, 0);
        BAR();
        STAGEX(t + 2, 0);
        BAR();
        MFMA16(av1, 1, 1);
        if (t >= NT1 - 2) { WAITV0(); } else { WAITV6(); }
        BAR();
    }

    float iv[4];
    #pragma unroll
    for (int fj = 0; fj < 4; ++fj)
        iv[fj] = invi[bn + wn * 64 + fj * 16 + row16];
    #pragma unroll
    for (int fi = 0; fi < 8; ++fi) {
        int crow = bm + wm * 128 + fi * 16 + kgrp * 4;
        #pragma unroll
        for (int fj = 0; fj < 4; ++fj) {
            int ccol = bn + wn * 64 + fj * 16 + row16;
            f32x4 v = acc[fi][fj];
            #pragma unroll
            for (int r = 0; r < 4; ++r)
                C[(size_t)(crow + r) * NUPAD + ccol] = f2h(v[r] * iv[fj]);
        }
    }
}

// ---- fused 9-tap fuse_diag + masked softmax; 8 consecutive sb per block ----
// (R9/R11/R13-proven optimum: 8-sb batching + global_load_lds DMA row staging,
//  213 us thrice-validated. Batching curve mapped: 4 < 8 > 16 under both
//  scalar (R7) and DMA (R12) staging. FROZEN — final configuration.)
__global__ __launch_bounds__(512) void fuse_softmax_kernel(const unsigned short* __restrict__ Scc4,
        const int* __restrict__ hdr, const short* __restrict__ tapu,
        unsigned short* __restrict__ Pc4) {
    __shared__ unsigned short lrow[3][NUPAD];
    __shared__ float redm[8][8], reds[8][8];
    int gimg = blockIdx.y;
    const unsigned short* Scc = Scc4 + (size_t)gimg * 4096 * NUPAD;
    int bid = blockIdx.x;                       // [0,512)
    int sb0 = ((bid & 7) << 9) + ((bid >> 3) << 3);
    int tid = threadIdx.x;
    int lane = tid & 63, wv = tid >> 6;
    int n_act = hdr[gimg * 4];
    int n_u = hdr[gimg * 4 + 1];
    int nu_s = (n_u + 511) & ~511;              // 512-multiple: full waves only
    if (nu_s > NUPAD) nu_s = NUPAD;
    bool actv = tid < n_act;
    short tp[9];
    if (actv) {
        const short* tpp = tapu + ((size_t)gimg * NACTPAD + tid) * 12;
        #pragma unroll
        for (int t = 0; t < 9; ++t) tp[t] = tpp[t];
    }
    float s[8] = {0.f, 0.f, 0.f, 0.f, 0.f, 0.f, 0.f, 0.f};
    for (int ph = 0; ph < 10; ++ph) {
        int tt = sb0 - 1 + ph;
        int ok = (tt >= 0 && tt < 4096);
        int ta = ok ? ((tt & 63) << 6) + (tt >> 6) : 0;
        int vmask = 0;
        #pragma unroll
        for (int dp = 0; dp < 3; ++dp) {
            int ra = ta + dp - 1;
            if (ok && ra >= 0 && ra < 4096) {
                vmask |= 1 << dp;
                const unsigned short* src = Scc + (size_t)ra * NUPAD;
                for (int u = tid * 8; u < nu_s; u += 4096)
                    __builtin_amdgcn_global_load_lds(
                        (const uint32_t*)(const void*)(src + u),
                        (uint32_t*)(void*)&lrow[dp][u], 16, 0, 0);
            }
        }
        __syncthreads();
        if (actv) {
            #pragma unroll
            for (int j = 0; j < 8; ++j) {
                int ei = ph - j;
                if (ei >= 0 && ei < 3) {
                    #pragma unroll
                    for (int dp = 0; dp < 3; ++dp) {
                        if ((vmask >> dp) & 1) {
                            int u = tp[ei * 3 + dp];
                            if (u >= 0) s[j] += h2f(lrow[dp][u]);
                        }
                    }
                }
            }
        }
        __syncthreads();
    }
    float m[8], e[8];
    #pragma unroll
    for (int j = 0; j < 8; ++j) {
        float x = actv ? SSCALE * s[j] : -3.0e38f;
        for (int off = 32; off > 0; off >>= 1) x = fmaxf(x, __shfl_xor(x, off, 64));
        if (lane == 0) redm[wv][j] = x;
    }
    __syncthreads();
    #pragma unroll
    for (int j = 0; j < 8; ++j) {
        float mm = -3.0e38f;
        #pragma unroll
        for (int w2 = 0; w2 < 8; ++w2) mm = fmaxf(mm, redm[w2][j]);
        m[j] = fmaxf(mm, 0.f);
        e[j] = actv ? __expf(SSCALE * s[j] - m[j]) : 0.f;
        float sm = e[j];
        for (int off = 32; off > 0; off >>= 1) sm += __shfl_xor(sm, off, 64);
        if (lane == 0) reds[wv][j] = sm;
    }
    __syncthreads();
    #pragma unroll
    for (int j = 0; j < 8; ++j) {
        float S = 0.f;
        #pragma unroll
        for (int w2 = 0; w2 < 8; ++w2) S += reds[w2][j];
        float denom = S + (4096.f - (float)n_act) * __expf(-m[j]);
        int sbj = sb0 + j;
        int b = ((sbj & 63) << 6) + (sbj >> 6);
        Pc4[(size_t)gimg * 4096 * NACTPAD + (size_t)b * NACTPAD + tid] = f2h(actv ? e[j] / denom : 0.f);
    }
}

// ---------- GEMM2 (128x128 NT), fp16 in/out, dynamic K, 2-phase dbuf ----------
// (R3-proven form; R6's 128x256/8-wave retile regressed ~2.6 us. FROZEN.)
#define G2STAGE(bs, kk) do {                                                            \
    _Pragma("unroll")                                                                   \
    for (int r_ = 0; r_ < 4; ++r_) {                                                    \
        int row_ = (wave << 5) + (r_ << 3) + rsub;                                      \
        const unsigned short* ga_ = A + (size_t)(bm + row_) * NACTPAD + (kk) + gcol;    \
        unsigned short* la_ = lds + (bs) * 16384 + (((wave << 5) + (r_ << 3)) << 6);    \
        __builtin_amdgcn_global_load_lds((const uint32_t*)(const void*)ga_,             \
                                         (uint32_t*)(void*)la_, 16, 0, 0);              \
        const unsigned short* gb_ = B + (size_t)(bn + row_) * NACTPAD + (kk) + gcol;    \
        unsigned short* lb_ = lds + (bs) * 16384 + 8192 + (((wave << 5) + (r_ << 3)) << 6); \
        __builtin_amdgcn_global_load_lds((const uint32_t*)(const void*)gb_,             \
                                         (uint32_t*)(void*)lb_, 16, 0, 0);              \
    } } while (0)

__global__ __launch_bounds__(256) void gemm2_nt(
        const unsigned short* __restrict__ BGTc4, const unsigned short* __restrict__ Pc4,
        const int* __restrict__ hdr, unsigned short* __restrict__ OUTT4) {
    __shared__ unsigned short lds[2 * 16384];   // 64 KB: 2 bufs x (A 16KB + B 16KB)
    const int gimg = blockIdx.z;
    const unsigned short* A = BGTc4 + (size_t)gimg * K1 * NACTPAD;
    const unsigned short* B = Pc4 + (size_t)gimg * 4096 * NACTPAD;
    unsigned short* C = OUTT4 + (size_t)gimg * K1 * LVAL;
    int n_act = hdr[gimg * 4];
    int kend = (n_act + 63) & ~63;
    if (kend < 64) kend = 64;
    const int tid = threadIdx.x;
    const int wave = tid >> 6, lane = tid & 63;
    const int wm = wave >> 1, wn = wave & 1;
    const int bm = blockIdx.y << 7, bn = blockIdx.x << 7;
    const int rsub = lane >> 3, csub = lane & 7;
    const int gcol = (csub ^ rsub) << 3;
    const int row16 = lane & 15, kgrp = lane >> 4;
    const int sw = (row16 & 7) << 3;

    f32x4 acc[4][4];
    #pragma unroll
    for (int i = 0; i < 4; ++i)
        #pragma unroll
        for (int j = 0; j < 4; ++j)
            acc[i][j] = (f32x4){0.f, 0.f, 0.f, 0.f};

    G2STAGE(0, 0);
    WAITV0();
    __syncthreads();
    int nt = kend >> 6;
    for (int t = 0; t < nt; ++t) {
        const int cs = t & 1;
        if (t + 1 < nt) G2STAGE(cs ^ 1, (t + 1) << 6);
        const unsigned short* Asm = lds + cs * 16384;
        const unsigned short* Bsm = lds + cs * 16384 + 8192;
        #pragma unroll
        for (int s = 0; s < 2; ++s) {
            half8 af[4], bfr[4];
            #pragma unroll
            for (int fi = 0; fi < 4; ++fi) {
                int ar = (wm << 6) + (fi << 4) + row16;
                af[fi] = *(const half8*)(Asm + (ar << 6) + (((s << 5) + (kgrp << 3)) ^ sw));
            }
            #pragma unroll
            for (int fj = 0; fj < 4; ++fj) {
                int br = (wn << 6) + (fj << 4) + row16;
                bfr[fj] = *(const half8*)(Bsm + (br << 6) + (((s << 5) + (kgrp << 3)) ^ sw));
            }
            #pragma unroll
            for (int fi = 0; fi < 4; ++fi)
                #pragma unroll
                for (int fj = 0; fj < 4; ++fj)
                    acc[fi][fj] = __builtin_amdgcn_mfma_f32_16x16x32_f16(
                        af[fi], bfr[fj], acc[fi][fj], 0, 0, 0);
        }
        WAITV0();
        __syncthreads();
    }
    #pragma unroll
    for (int fi = 0; fi < 4; ++fi) {
        int crow = bm + (wm << 6) + (fi << 4) + (kgrp << 2);
        #pragma unroll
        for (int fj = 0; fj < 4; ++fj) {
            int ccol = bn + (wn << 6) + (fj << 4) + row16;
            f32x4 v = acc[fi][fj];
            #pragma unroll
            for (int r = 0; r < 4; ++r)
                C[(size_t)(crow + r) * LVAL + ccol] = f2h(v[r]);
        }
    }
}

// ---- transposed-conv scatter (fp16 OUTT); k2 = (i*3+j)*128 + ch ----
__global__ void scatter_kernel(const unsigned short* __restrict__ OUTT4,
                               float* __restrict__ out) {
    int gimg = blockIdx.y;
    const unsigned short* OUTT = OUTT4 + (size_t)gimg * K1 * LVAL;
    float* oi = out + (size_t)gimg * CCH * HH * WW;
    int idx = blockIdx.x * 256 + threadIdx.x;
    int x = idx & 127;
    int y = (idx >> 7) & 127;
    int ch = idx >> 14;
    int yy = y < 127 ? y : 126;
    int xx = x < 127 ? x : 126;
    int hy[2], iy[2], ny;
    if (yy & 1) { hy[0] = (yy + 1) >> 1; iy[0] = 0; hy[1] = (yy - 1) >> 1; iy[1] = 2; ny = 2; }
    else        { hy[0] = yy >> 1;       iy[0] = 1; ny = 1; }
    int wx[2], jx[2], nx;
    if (xx & 1) { wx[0] = (xx + 1) >> 1; jx[0] = 0; wx[1] = (xx - 1) >> 1; jx[1] = 2; nx = 2; }
    else        { wx[0] = xx >> 1;       jx[0] = 1; nx = 1; }
    float s = 0.f;
    for (int u = 0; u < ny; ++u)
        for (int v = 0; v < nx; ++v) {
            int k2 = (iy[u] * 3 + jx[v]) * 128 + ch;
            s += h2f(OUTT[(size_t)k2 * LVAL + (hy[u] << 6) + wx[v]]);
        }
    oi[idx] = s * 0.25f;
}

extern "C" void kernel_launch(void* const* d_in, const int* in_sizes, int n_in,
                              void* d_out, int out_size, void* d_ws, size_t ws_size,
                              hipStream_t stream) {
    const float* f = (const float*)d_in[0];
    const float* b = (const float*)d_in[1];
    const float* mask = (const float*)d_in[2];
    float* out = (float*)d_out;
    char* ws = (char*)d_ws;

    // layout (bytes)
    const size_t oQ    = 0;              // 65,536
    const size_t oACT  = 65536;          // 8,192
    const size_t oUL   = 73728;          // 32,768
    const size_t oTAP  = 106496;         // 49,152
    const size_t oHDR  = 155648;         // 1,024
    const size_t oINVN = 156672;         // 32,768
    const size_t oBGTC = 189440;         // 4,718,592
    const size_t oPC   = 4908032;        // 16,777,216
    const size_t oFPAD = 21685248;       // 4,460,544
    const size_t oBPAD = 26145792;       // 4,460,544
    const size_t oSCC  = 30606336;       // 4*4096*2048*2 = 67,108,864
    // total ~93 MB

    float* Q   = (float*)(ws + oQ);
    int*   ACT = (int*)(ws + oACT);
    int*   UL  = (int*)(ws + oUL);
    short* TAP = (short*)(ws + oTAP);
    int*   HDR = (int*)(ws + oHDR);
    float* INVN = (float*)(ws + oINVN);
    unsigned short* BGTc4 = (unsigned short*)(ws + oBGTC);
    unsigned short* Pc4   = (unsigned short*)(ws + oPC);
    unsigned short* fpad4 = (unsigned short*)(ws + oFPAD);
    unsigned short* bpad4 = (unsigned short*)(ws + oBPAD);
    unsigned short* Scc4 = (unsigned short*)(ws + oSCC);
    unsigned short* OUTT4 = (unsigned short*)(ws + oSCC);  // Scc dead after fuse
    float* SSQ = (float*)(ws + oSCC);    // 9-tap Q sums; dead before gemm1 writes Scc

    dst_kernel<<<dim3(64, 4, 8), 256, 0, stream>>>(f, b, fpad4, bpad4);
    qk_border_kernel<<<dim3(1297, 4), 256, 0, stream>>>(fpad4, bpad4, Q);
    ss_kernel<<<dim3(16, 4), 256, 0, stream>>>(Q, SSQ);
    compact_kernel<<<4, 1024, 0, stream>>>(mask, SSQ, ACT, UL, TAP, INVN, HDR);
    prep_bgtc_kernel<<<dim3(2304, 4), 256, 0, stream>>>(b, ACT, HDR, BGTc4);

    gemm1_8phase<<<dim3(128, 4), 512, 0, stream>>>(fpad4, bpad4, Scc4, UL, HDR, INVN);
    fuse_softmax_kernel<<<dim3(512, 4), 512, 0, stream>>>(Scc4, HDR, TAP, Pc4);

    gemm2_nt<<<dim3(32, 9, 4), 256, 0, stream>>>(BGTc4, Pc4, HDR, OUTT4);
    scatter_kernel<<<dim3(8192, 4), 256, 0, stream>>>(OUTT4, out);
    (void)in_sizes; (void)n_in; (void)out_size; (void)ws_size;
}

// Round 15
// 212.659 us; speedup vs baseline: 1.0114x; 1.0009x over previous
//
#include <hip/hip_runtime.h>
#include <cstdint>

#define LVAL 4096
#define K1 1152
#define NT1 18
#define CCH 128
#define HH 128
#define WW 128
#define SSCALE 10.0f
#define NUPAD 2048
#define NACTPAD 512
#define PADPIX 4356          // 66*66
#define PIMG 557568          // 66*66*128 fp16 per image

typedef __attribute__((ext_vector_type(8))) short short8;
typedef __attribute__((ext_vector_type(8))) _Float16 half8;
typedef __attribute__((ext_vector_type(4))) float f32x4;

static __device__ __forceinline__ int clampi(int v, int lo, int hi) {
    return v < lo ? lo : (v > hi ? hi : v);
}
static __device__ __forceinline__ unsigned short f2h(float x) {
    union { _Float16 h; unsigned short u; } c; c.h = (_Float16)x; return c.u;
}
static __device__ __forceinline__ float h2f(unsigned short u) {
    union { _Float16 h; unsigned short u; } c; c.u = u; return (float)c.h;
}

// ---- downsample + transpose + fp16 straight into padded interiors ----
__global__ __launch_bounds__(256) void dst_kernel(const float* __restrict__ f,
        const float* __restrict__ b, unsigned short* __restrict__ fpad4,
        unsigned short* __restrict__ bpad4) {
    __shared__ float t[32][65];
    int h = blockIdx.x;          // 0..63
    int cg = blockIdx.y;         // 0..3
    int za = blockIdx.z;
    int img = za >> 1, arr = za & 1;
    const float* src = (arr ? b : f) + (size_t)img * CCH * HH * WW;
    unsigned short* dst = (arr ? bpad4 : fpad4) + (size_t)img * PIMG;
    int tid = threadIdx.x;
    int w = tid & 63, csub = tid >> 6;
    #pragma unroll
    for (int cc = 0; cc < 8; ++cc) {
        int cl = csub * 8 + cc;
        int ch = cg * 32 + cl;
        t[cl][w] = src[(size_t)ch * (HH * WW) + (2 * h) * WW + (2 * w)];
    }
    __syncthreads();
    int c = tid & 31, pr = tid >> 5;
    #pragma unroll
    for (int pp = 0; pp < 8; ++pp) {
        int w2 = pr * 8 + pp;
        dst[((size_t)(h + 1) * 66 + (w2 + 1)) * 128 + cg * 32 + c] = f2h(t[c][w2]);
    }
}

// ---- merged: Q norms (blocks <1024) + border fill (blocks >=1024) ----
__global__ __launch_bounds__(256) void qk_border_kernel(unsigned short* __restrict__ fpad4,
        unsigned short* __restrict__ bpad4, float* __restrict__ Q) {
    int img = blockIdx.y;
    int tid = threadIdx.x;
    if (blockIdx.x < 1024) {
        int lane = tid & 63, sub = tid >> 6;
        int pix = blockIdx.x * 4 + sub;
        const unsigned short* row = bpad4 + (size_t)img * PIMG
                                    + ((size_t)((pix >> 6) + 1) * 66 + (pix & 63) + 1) * 128;
        uint32_t hv = *(const uint32_t*)(row + lane * 2);
        float a = h2f((unsigned short)(hv & 0xffff));
        float b2 = h2f((unsigned short)(hv >> 16));
        float s = a * a + b2 * b2;
        for (int off = 32; off > 0; off >>= 1) s += __shfl_xor(s, off, 64);
        if (lane == 0) Q[img * 4096 + pix] = s;
    } else {
        int id = (blockIdx.x - 1024) * 256 + tid;
        if (id >= PADPIX * 16) return;
        int pix = id >> 4, cg = (id & 15) << 3;
        int hp = pix / 66, wp = pix - hp * 66;
        if (hp >= 1 && hp <= 64 && wp >= 1 && wp <= 64) return;
        unsigned short* fp = fpad4 + (size_t)img * PIMG + (size_t)pix * 128 + cg;
        #pragma unroll
        for (int cc = 0; cc < 8; ++cc) fp[cc] = 0;
        int hs = clampi(hp - 1, 0, 63), wsx = clampi(wp - 1, 0, 63);
        const unsigned short* sb = bpad4 + (size_t)img * PIMG
                                   + ((size_t)(hs + 1) * 66 + (wsx + 1)) * 128 + cg;
        unsigned short* bp = bpad4 + (size_t)img * PIMG + (size_t)pix * 128 + cg;
        #pragma unroll
        for (int cc = 0; cc < 8; ++cc) bp[cc] = sb[cc];
    }
}

// ---- 9-tap clamped sum of Q (was compact's ssl pass; identical FP order) ----
__global__ __launch_bounds__(256) void ss_kernel(const float* __restrict__ Q,
                                                 float* __restrict__ SS) {
    int img = blockIdx.y;
    const float* Qi = Q + img * 4096;
    int a = blockIdx.x * 256 + threadIdx.x;    // grid.x = 16
    int hb = a >> 6, wb = a & 63;
    float s = 0.f;
    #pragma unroll
    for (int i = 0; i < 3; ++i)
        #pragma unroll
        for (int j2 = 0; j2 < 3; ++j2) {
            int hl = clampi(hb + i - 1, 0, 63);
            int wl = clampi(wb + j2 - 1, 0, 63);
            s += Qi[hl * 64 + wl];
        }
    SS[img * 4096 + a] = s;
}

// ---- compaction: act list, union list/map, taps, compact inv-norms ----
__global__ __launch_bounds__(1024) void compact_kernel(const float* __restrict__ mask,
        const float* __restrict__ ssq, int* __restrict__ act, int* __restrict__ ulist,
        short* __restrict__ tapu, float* __restrict__ invn, int* __restrict__ hdr) {
    int img = blockIdx.x;
    const float* mk = mask + (size_t)img * HH * WW;
    const float* ssi = ssq + img * 4096;
    int* acti = act + img * NACTPAD;
    int* uli = ulist + img * NUPAD;
    short* tpi = tapu + (size_t)img * NACTPAD * 12;
    float* invi = invn + (size_t)img * NUPAD;
    int* hd = hdr + img * 4;
    int tid = threadIdx.x;
    int lane = tid & 63, wv = tid >> 6;
    __shared__ unsigned char flag[4096];
    __shared__ short umap[4096];
    __shared__ int actl[NACTPAD];
    __shared__ int wsum[16], woff[16];
    __shared__ int tot;

    int loc[4];
    int cnt = 0;
    #pragma unroll
    for (int k = 0; k < 4; ++k) {
        int a = tid * 4 + k;
        int hb = a >> 6, wb = a & 63;
        float s = 0.f;
        for (int di = -1; di <= 1; ++di)
            for (int dj = -1; dj <= 1; ++dj) {
                int hh = hb + di, w2 = wb + dj;
                if (hh >= 0 && hh < 64 && w2 >= 0 && w2 < 64)
                    s += mk[(2 * hh) * WW + 2 * w2];
            }
        loc[k] = (s == 0.f) ? 1 : 0;
        cnt += loc[k];
    }
    int pre = cnt;
    for (int off = 1; off < 64; off <<= 1) { int v = __shfl_up(pre, off, 64); if (lane >= off) pre += v; }
    if (lane == 63) wsum[wv] = pre;
    __syncthreads();
    if (tid == 0) { int a2 = 0; for (int w2 = 0; w2 < 16; ++w2) { woff[w2] = a2; a2 += wsum[w2]; } tot = a2; }
    __syncthreads();
    int base = woff[wv] + pre - cnt;
    int n_act = tot < NACTPAD ? tot : NACTPAD;
    {
        int p = base;
        #pragma unroll
        for (int k = 0; k < 4; ++k)
            if (loc[k]) { if (p < NACTPAD) { acti[p] = tid * 4 + k; actl[p] = tid * 4 + k; } p++; }
    }
    #pragma unroll
    for (int k = 0; k < 4; ++k) { flag[tid * 4 + k] = 0; umap[tid * 4 + k] = -1; }
    __syncthreads();
    for (int j = tid; j < n_act; j += 1024) {
        int a = actl[j];
        int sa = ((a & 63) << 6) + (a >> 6);
        #pragma unroll
        for (int ei = 0; ei < 3; ++ei) {
            int tbt = sa + ei - 1;
            if (tbt < 0 || tbt >= 4096) continue;
            int tb = ((tbt & 63) << 6) + (tbt >> 6);
            #pragma unroll
            for (int d = -1; d <= 1; ++d) {
                int rb = tb + d;
                if (rb >= 0 && rb < 4096) flag[rb] = 1;
            }
        }
    }
    __syncthreads();
    int cnt2 = 0;
    int loc2[4];
    #pragma unroll
    for (int k = 0; k < 4; ++k) { loc2[k] = flag[tid * 4 + k]; cnt2 += loc2[k]; }
    int pre2 = cnt2;
    for (int off = 1; off < 64; off <<= 1) { int v = __shfl_up(pre2, off, 64); if (lane >= off) pre2 += v; }
    if (lane == 63) wsum[wv] = pre2;
    __syncthreads();
    if (tid == 0) { int a2 = 0; for (int w2 = 0; w2 < 16; ++w2) { woff[w2] = a2; a2 += wsum[w2]; } tot = a2; }
    __syncthreads();
    int base2 = woff[wv] + pre2 - cnt2;
    int n_u = tot < NUPAD ? tot : NUPAD;
    {
        int p = base2;
        #pragma unroll
        for (int k = 0; k < 4; ++k)
            if (loc2[k]) { int ci = tid * 4 + k; if (p < NUPAD) { uli[p] = ci; umap[ci] = (short)p; } p++; }
    }
    __syncthreads();
    for (int j = tid; j < n_act; j += 1024) {
        int a = actl[j];
        int sa = ((a & 63) << 6) + (a >> 6);
        #pragma unroll
        for (int ei = 0; ei < 3; ++ei) {
            int tbt = sa + ei - 1;
            int ok = (tbt >= 0 && tbt < 4096);
            int tb = ok ? ((tbt & 63) << 6) + (tbt >> 6) : 0;
            #pragma unroll
            for (int d = -1; d <= 1; ++d) {
                short v = -1;
                if (ok) { int rb = tb + d; if (rb >= 0 && rb < 4096) v = umap[rb]; }
                tpi[j * 12 + ei * 3 + d + 1] = v;
            }
        }
    }
    for (int u = tid; u < NUPAD; u += 1024) invi[u] = 0.f;
    __syncthreads();
    for (int ci = tid; ci < 4096; ci += 1024) {
        if (flag[ci]) {
            int u = umap[ci];
            if (u >= 0) invi[u] = 1.f / fmaxf(sqrtf(ssi[ci]), 1e-4f);
        }
    }
    if (tid == 0) { hd[0] = n_act; hd[1] = n_u; }
}

// ---- BGT_c[k2][j] (compact columns, fp16), k2 = q*128+ch; grid.y = img ----
__global__ void prep_bgtc_kernel(const float* __restrict__ b, const int* __restrict__ act,
                                 const int* __restrict__ hdr, unsigned short* __restrict__ BGTc4) {
    int gimg = blockIdx.y;
    const float* bi = b + (size_t)gimg * CCH * HH * WW;
    int idx = blockIdx.x * 256 + threadIdx.x;
    int k2 = idx >> 9, j = idx & 511;
    int n_act = hdr[gimg * 4];
    unsigned short v = 0;
    if (j < n_act) {
        int a = act[gimg * NACTPAD + j];
        int ch = k2 & 127, q = k2 >> 7;
        int i = q / 3, jj = q - i * 3;
        int y = clampi(2 * (a >> 6) + i - 1, 0, 127);
        int x = clampi(2 * (a & 63) + jj - 1, 0, 127);
        v = f2h(bi[(size_t)ch * (HH * WW) + y * WW + x]);
    }
    BGTc4[(size_t)gimg * K1 * NACTPAD + idx] = v;
}

// ---------- GEMM1: 256x256 tile, BK=64, 8 waves, 8-phase counted-vmcnt, fp16 ----------
// (R1-proven form, 78 us. Structural variants all regressed: R2 32x32-MFMA
//  (bank conflicts), R4 BK=32/2-block (82), R5 128x256 (92). FROZEN.)
#define BAR() __builtin_amdgcn_s_barrier()
#define WAITV6() asm volatile("s_waitcnt vmcnt(6)" ::: "memory")
#define WAITV0() asm volatile("s_waitcnt vmcnt(0)" ::: "memory")

// tile t in [0,18): K-chunk t*64 -> shift q = t>>1, half = t&1 (same for A and B)
#define STAGEX(tt, h) do {                                                              \
    int t_ = (tt);                                                                      \
    if (t_ < NT1) {                                                                     \
        const int isB_ = ((h) == 1 || (h) == 2);                                        \
        const int hi_ = ((h) >= 2) ? 1 : 0;                                             \
        int q_ = t_ >> 1;                                                               \
        int qi_ = (q_ * 11) >> 5;                                                       \
        int qj_ = q_ - qi_ * 3;                                                         \
        int toff_ = ((qi_ * 66 + qj_) << 7) + ((t_ & 1) << 6);                          \
        _Pragma("unroll")                                                               \
        for (int r_ = 0; r_ < 2; ++r_) {                                                \
            int sl_ = hi_ * 2 + r_;                                                     \
            const unsigned short* g_ = (isB_ ? bR[sl_] : aR[sl_]) + toff_;              \
            unsigned short* l_ = lds + (isB_ ? 32768 : 0) + ((t_ & 1) << 14)            \
                                 + ((hi_ * 128 + r_ * 64 + swb) << 6);                  \
            __builtin_amdgcn_global_load_lds((const uint32_t*)(const void*)g_,          \
                                             (uint32_t*)(void*)l_, 16, 0, 0);           \
        }                                                                               \
    } } while (0)

#define LDA4(dst, cur, ah) do {                                                         \
    _Pragma("unroll")                                                                   \
    for (int f_ = 0; f_ < 4; ++f_)                                                      \
    { _Pragma("unroll")                                                                 \
      for (int s_ = 0; s_ < 2; ++s_) {                                                  \
        int row_ = wm * 128 + ((ah) * 4 + f_) * 16 + row16;                             \
        int cs_ = ((s_ << 2) + kgrp) ^ (row16 & 7);                                     \
        dst[f_ * 2 + s_] = *(const half8*)(lds + ((cur) << 14) + (row_ << 6) + (cs_ << 3)); \
    } } } while (0)

#define LDB2(cur, bh) do {                                                              \
    _Pragma("unroll")                                                                   \
    for (int f_ = 0; f_ < 2; ++f_)                                                      \
    { _Pragma("unroll")                                                                 \
      for (int s_ = 0; s_ < 2; ++s_) {                                                  \
        int row_ = wn * 64 + ((bh) * 2 + f_) * 16 + row16;                              \
        int cs_ = ((s_ << 2) + kgrp) ^ (row16 & 7);                                     \
        bv[(bh) * 4 + f_ * 2 + s_] = *(const half8*)(lds + 32768 + ((cur) << 14) + (row_ << 6) + (cs_ << 3)); \
    } } } while (0)

#define MFMA16(va, ai, bj) do {                                                         \
    __builtin_amdgcn_s_setprio(1);                                                      \
    _Pragma("unroll")                                                                   \
    for (int f_ = 0; f_ < 4; ++f_)                                                      \
    { _Pragma("unroll")                                                                 \
      for (int g_ = 0; g_ < 2; ++g_)                                                    \
      { _Pragma("unroll")                                                               \
        for (int s_ = 0; s_ < 2; ++s_)                                                  \
            acc[(ai) * 4 + f_][(bj) * 2 + g_] = __builtin_amdgcn_mfma_f32_16x16x32_f16( \
                va[f_ * 2 + s_], bv[(bj) * 4 + g_ * 2 + s_], acc[(ai) * 4 + f_][(bj) * 2 + g_], 0, 0, 0); \
    } } __builtin_amdgcn_s_setprio(0); } while (0)

__global__ __launch_bounds__(512, 2) void gemm1_8phase(const unsigned short* __restrict__ fpad4,
        const unsigned short* __restrict__ bpad4, unsigned short* __restrict__ Scc4,
        const int* __restrict__ ulist, const int* __restrict__ hdr,
        const float* __restrict__ invn) {
    __shared__ unsigned short lds[65536];
    const int gimg = blockIdx.y;
    const unsigned short* fpadI = fpad4 + (size_t)gimg * PIMG;
    const unsigned short* bpadI = bpad4 + (size_t)gimg * PIMG;
    unsigned short* C = Scc4 + (size_t)gimg * 4096 * NUPAD;
    const int* uli = ulist + gimg * NUPAD;
    const float* invi = invn + (size_t)gimg * NUPAD;
    const int n_u = hdr[gimg * 4 + 1];
    const int tid = threadIdx.x;
    const int lane = tid & 63;
    const int wave = tid >> 6;
    const int wm = wave >> 2, wn = wave & 3;
    const int row16 = lane & 15, kgrp = lane >> 4;
    const int srow = tid >> 3, schunk = tid & 7;
    const int swb = wave << 3;
    int bid = blockIdx.x;                       // 128 = 8 XCDs x 16
    int wgid = ((bid & 7) << 4) + (bid >> 3);
    const int bm = (wgid >> 3) << 8;            // 16 row tiles
    const int bn = (wgid & 7) << 8;             // 8 col tiles
    if (bn >= ((n_u + 255) & ~255)) return;

    const int ck8 = (schunk ^ (srow & 7)) << 3;
    const unsigned short* aR[4];
    const unsigned short* bR[4];
    #pragma unroll
    for (int i2 = 0; i2 < 4; ++i2) {
        int rowp = i2 * 64 + srow;
        int ar = bm + rowp;
        aR[i2] = fpadI + (size_t)((ar >> 6) * 66 + (ar & 63)) * 128 + ck8;
        int uu = bn + rowp;
        int brow = uli[uu < n_u ? uu : n_u - 1];
        bR[i2] = bpadI + (size_t)((brow >> 6) * 66 + (brow & 63)) * 128 + ck8;
    }

    f32x4 acc[8][4];
    #pragma unroll
    for (int i = 0; i < 8; ++i)
        #pragma unroll
        for (int j = 0; j < 4; ++j)
            acc[i][j] = (f32x4){0.f, 0.f, 0.f, 0.f};

    STAGEX(0, 1); STAGEX(0, 2); STAGEX(0, 0); STAGEX(0, 3);
    STAGEX(1, 1); STAGEX(1, 2); STAGEX(1, 0);
    WAITV6();
    BAR();

    half8 av0[8], av1[8], bv[8];
    for (int t = 0; t < NT1; ++t) {
        const int cur = t & 1;
        LDA4(av0, cur, 0);
        LDB2(cur, 0);
        LDB2(cur, 1);
        STAGEX(t + 1, 3);
        BAR();
        MFMA16(av0, 0, 0);
        LDA4(av1, cur, 1);
        BAR();
        STAGEX(t + 2, 1);
        BAR();
        MFMA16(av0, 0, 1);
        BAR();
        STAGEX(t + 2, 2);
        BAR();
        MFMA16(av1, 1, 0);
        BAR();
        STAGEX(t + 2, 0);
        BAR();
        MFMA16(av1, 1, 1);
        if (t >= NT1 - 2) { WAITV0(); } else { WAITV6(); }
        BAR();
    }

    float iv[4];
    #pragma unroll
    for (int fj = 0; fj < 4; ++fj)
        iv[fj] = invi[bn + wn * 64 + fj * 16 + row16];
    #pragma unroll
    for (int fi = 0; fi < 8; ++fi) {
        int crow = bm + wm * 128 + fi * 16 + kgrp * 4;
        #pragma unroll
        for (int fj = 0; fj < 4; ++fj) {
            int ccol = bn + wn * 64 + fj * 16 + row16;
            f32x4 v = acc[fi][fj];
            #pragma unroll
            for (int r = 0; r < 4; ++r)
                C[(size_t)(crow + r) * NUPAD + ccol] = f2h(v[r] * iv[fj]);
        }
    }
}

// ---- fused 9-tap fuse_diag + masked softmax; 8 consecutive sb per block ----
// (R9/R11/R13/R14-proven optimum: 8-sb batching + global_load_lds DMA row
//  staging, 213 us four-times-validated. Batching curve mapped: 4 < 8 > 16
//  under both scalar (R7) and DMA (R12) staging. FROZEN — final configuration.)
__global__ __launch_bounds__(512) void fuse_softmax_kernel(const unsigned short* __restrict__ Scc4,
        const int* __restrict__ hdr, const short* __restrict__ tapu,
        unsigned short* __restrict__ Pc4) {
    __shared__ unsigned short lrow[3][NUPAD];
    __shared__ float redm[8][8], reds[8][8];
    int gimg = blockIdx.y;
    const unsigned short* Scc = Scc4 + (size_t)gimg * 4096 * NUPAD;
    int bid = blockIdx.x;                       // [0,512)
    int sb0 = ((bid & 7) << 9) + ((bid >> 3) << 3);
    int tid = threadIdx.x;
    int lane = tid & 63, wv = tid >> 6;
    int n_act = hdr[gimg * 4];
    int n_u = hdr[gimg * 4 + 1];
    int nu_s = (n_u + 511) & ~511;              // 512-multiple: full waves only
    if (nu_s > NUPAD) nu_s = NUPAD;
    bool actv = tid < n_act;
    short tp[9];
    if (actv) {
        const short* tpp = tapu + ((size_t)gimg * NACTPAD + tid) * 12;
        #pragma unroll
        for (int t = 0; t < 9; ++t) tp[t] = tpp[t];
    }
    float s[8] = {0.f, 0.f, 0.f, 0.f, 0.f, 0.f, 0.f, 0.f};
    for (int ph = 0; ph < 10; ++ph) {
        int tt = sb0 - 1 + ph;
        int ok = (tt >= 0 && tt < 4096);
        int ta = ok ? ((tt & 63) << 6) + (tt >> 6) : 0;
        int vmask = 0;
        #pragma unroll
        for (int dp = 0; dp < 3; ++dp) {
            int ra = ta + dp - 1;
            if (ok && ra >= 0 && ra < 4096) {
                vmask |= 1 << dp;
                const unsigned short* src = Scc + (size_t)ra * NUPAD;
                for (int u = tid * 8; u < nu_s; u += 4096)
                    __builtin_amdgcn_global_load_lds(
                        (const uint32_t*)(const void*)(src + u),
                        (uint32_t*)(void*)&lrow[dp][u], 16, 0, 0);
            }
        }
        __syncthreads();
        if (actv) {
            #pragma unroll
            for (int j = 0; j < 8; ++j) {
                int ei = ph - j;
                if (ei >= 0 && ei < 3) {
                    #pragma unroll
                    for (int dp = 0; dp < 3; ++dp) {
                        if ((vmask >> dp) & 1) {
                            int u = tp[ei * 3 + dp];
                            if (u >= 0) s[j] += h2f(lrow[dp][u]);
                        }
                    }
                }
            }
        }
        __syncthreads();
    }
    float m[8], e[8];
    #pragma unroll
    for (int j = 0; j < 8; ++j) {
        float x = actv ? SSCALE * s[j] : -3.0e38f;
        for (int off = 32; off > 0; off >>= 1) x = fmaxf(x, __shfl_xor(x, off, 64));
        if (lane == 0) redm[wv][j] = x;
    }
    __syncthreads();
    #pragma unroll
    for (int j = 0; j < 8; ++j) {
        float mm = -3.0e38f;
        #pragma unroll
        for (int w2 = 0; w2 < 8; ++w2) mm = fmaxf(mm, redm[w2][j]);
        m[j] = fmaxf(mm, 0.f);
        e[j] = actv ? __expf(SSCALE * s[j] - m[j]) : 0.f;
        float sm = e[j];
        for (int off = 32; off > 0; off >>= 1) sm += __shfl_xor(sm, off, 64);
        if (lane == 0) reds[wv][j] = sm;
    }
    __syncthreads();
    #pragma unroll
    for (int j = 0; j < 8; ++j) {
        float S = 0.f;
        #pragma unroll
        for (int w2 = 0; w2 < 8; ++w2) S += reds[w2][j];
        float denom = S + (4096.f - (float)n_act) * __expf(-m[j]);
        int sbj = sb0 + j;
        int b = ((sbj & 63) << 6) + (sbj >> 6);
        Pc4[(size_t)gimg * 4096 * NACTPAD + (size_t)b * NACTPAD + tid] = f2h(actv ? e[j] / denom : 0.f);
    }
}

// ---------- GEMM2 (128x128 NT), fp16 in/out, dynamic K, 2-phase dbuf ----------
// (R3-proven form; R6's 128x256/8-wave retile regressed ~2.6 us. FROZEN.)
#define G2STAGE(bs, kk) do {                                                            \
    _Pragma("unroll")                                                                   \
    for (int r_ = 0; r_ < 4; ++r_) {                                                    \
        int row_ = (wave << 5) + (r_ << 3) + rsub;                                      \
        const unsigned short* ga_ = A + (size_t)(bm + row_) * NACTPAD + (kk) + gcol;    \
        unsigned short* la_ = lds + (bs) * 16384 + (((wave << 5) + (r_ << 3)) << 6);    \
        __builtin_amdgcn_global_load_lds((const uint32_t*)(const void*)ga_,             \
                                         (uint32_t*)(void*)la_, 16, 0, 0);              \
        const unsigned short* gb_ = B + (size_t)(bn + row_) * NACTPAD + (kk) + gcol;    \
        unsigned short* lb_ = lds + (bs) * 16384 + 8192 + (((wave << 5) + (r_ << 3)) << 6); \
        __builtin_amdgcn_global_load_lds((const uint32_t*)(const void*)gb_,             \
                                         (uint32_t*)(void*)lb_, 16, 0, 0);              \
    } } while (0)

__global__ __launch_bounds__(256) void gemm2_nt(
        const unsigned short* __restrict__ BGTc4, const unsigned short* __restrict__ Pc4,
        const int* __restrict__ hdr, unsigned short* __restrict__ OUTT4) {
    __shared__ unsigned short lds[2 * 16384];   // 64 KB: 2 bufs x (A 16KB + B 16KB)
    const int gimg = blockIdx.z;
    const unsigned short* A = BGTc4 + (size_t)gimg * K1 * NACTPAD;
    const unsigned short* B = Pc4 + (size_t)gimg * 4096 * NACTPAD;
    unsigned short* C = OUTT4 + (size_t)gimg * K1 * LVAL;
    int n_act = hdr[gimg * 4];
    int kend = (n_act + 63) & ~63;
    if (kend < 64) kend = 64;
    const int tid = threadIdx.x;
    const int wave = tid >> 6, lane = tid & 63;
    const int wm = wave >> 1, wn = wave & 1;
    const int bm = blockIdx.y << 7, bn = blockIdx.x << 7;
    const int rsub = lane >> 3, csub = lane & 7;
    const int gcol = (csub ^ rsub) << 3;
    const int row16 = lane & 15, kgrp = lane >> 4;
    const int sw = (row16 & 7) << 3;

    f32x4 acc[4][4];
    #pragma unroll
    for (int i = 0; i < 4; ++i)
        #pragma unroll
        for (int j = 0; j < 4; ++j)
            acc[i][j] = (f32x4){0.f, 0.f, 0.f, 0.f};

    G2STAGE(0, 0);
    WAITV0();
    __syncthreads();
    int nt = kend >> 6;
    for (int t = 0; t < nt; ++t) {
        const int cs = t & 1;
        if (t + 1 < nt) G2STAGE(cs ^ 1, (t + 1) << 6);
        const unsigned short* Asm = lds + cs * 16384;
        const unsigned short* Bsm = lds + cs * 16384 + 8192;
        #pragma unroll
        for (int s = 0; s < 2; ++s) {
            half8 af[4], bfr[4];
            #pragma unroll
            for (int fi = 0; fi < 4; ++fi) {
                int ar = (wm << 6) + (fi << 4) + row16;
                af[fi] = *(const half8*)(Asm + (ar << 6) + (((s << 5) + (kgrp << 3)) ^ sw));
            }
            #pragma unroll
            for (int fj = 0; fj < 4; ++fj) {
                int br = (wn << 6) + (fj << 4) + row16;
                bfr[fj] = *(const half8*)(Bsm + (br << 6) + (((s << 5) + (kgrp << 3)) ^ sw));
            }
            #pragma unroll
            for (int fi = 0; fi < 4; ++fi)
                #pragma unroll
                for (int fj = 0; fj < 4; ++fj)
                    acc[fi][fj] = __builtin_amdgcn_mfma_f32_16x16x32_f16(
                        af[fi], bfr[fj], acc[fi][fj], 0, 0, 0);
        }
        WAITV0();
        __syncthreads();
    }
    #pragma unroll
    for (int fi = 0; fi < 4; ++fi) {
        int crow = bm + (wm << 6) + (fi << 4) + (kgrp << 2);
        #pragma unroll
        for (int fj = 0; fj < 4; ++fj) {
            int ccol = bn + (wn << 6) + (fj << 4) + row16;
            f32x4 v = acc[fi][fj];
            #pragma unroll
            for (int r = 0; r < 4; ++r)
                C[(size_t)(crow + r) * LVAL + ccol] = f2h(v[r]);
        }
    }
}

// ---- transposed-conv scatter (fp16 OUTT); k2 = (i*3+j)*128 + ch ----
__global__ void scatter_kernel(const unsigned short* __restrict__ OUTT4,
                               float* __restrict__ out) {
    int gimg = blockIdx.y;
    const unsigned short* OUTT = OUTT4 + (size_t)gimg * K1 * LVAL;
    float* oi = out + (size_t)gimg * CCH * HH * WW;
    int idx = blockIdx.x * 256 + threadIdx.x;
    int x = idx & 127;
    int y = (idx >> 7) & 127;
    int ch = idx >> 14;
    int yy = y < 127 ? y : 126;
    int xx = x < 127 ? x : 126;
    int hy[2], iy[2], ny;
    if (yy & 1) { hy[0] = (yy + 1) >> 1; iy[0] = 0; hy[1] = (yy - 1) >> 1; iy[1] = 2; ny = 2; }
    else        { hy[0] = yy >> 1;       iy[0] = 1; ny = 1; }
    int wx[2], jx[2], nx;
    if (xx & 1) { wx[0] = (xx + 1) >> 1; jx[0] = 0; wx[1] = (xx - 1) >> 1; jx[1] = 2; nx = 2; }
    else        { wx[0] = xx >> 1;       jx[0] = 1; nx = 1; }
    float s = 0.f;
    for (int u = 0; u < ny; ++u)
        for (int v = 0; v < nx; ++v) {
            int k2 = (iy[u] * 3 + jx[v]) * 128 + ch;
            s += h2f(OUTT[(size_t)k2 * LVAL + (hy[u] << 6) + wx[v]]);
        }
    oi[idx] = s * 0.25f;
}

extern "C" void kernel_launch(void* const* d_in, const int* in_sizes, int n_in,
                              void* d_out, int out_size, void* d_ws, size_t ws_size,
                              hipStream_t stream) {
    const float* f = (const float*)d_in[0];
    const float* b = (const float*)d_in[1];
    const float* mask = (const float*)d_in[2];
    float* out = (float*)d_out;
    char* ws = (char*)d_ws;

    // layout (bytes)
    const size_t oQ    = 0;              // 65,536
    const size_t oACT  = 65536;          // 8,192
    const size_t oUL   = 73728;          // 32,768
    const size_t oTAP  = 106496;         // 49,152
    const size_t oHDR  = 155648;         // 1,024
    const size_t oINVN = 156672;         // 32,768
    const size_t oBGTC = 189440;         // 4,718,592
    const size_t oPC   = 4908032;        // 16,777,216
    const size_t oFPAD = 21685248;       // 4,460,544
    const size_t oBPAD = 26145792;       // 4,460,544
    const size_t oSCC  = 30606336;       // 4*4096*2048*2 = 67,108,864
    // total ~93 MB

    float* Q   = (float*)(ws + oQ);
    int*   ACT = (int*)(ws + oACT);
    int*   UL  = (int*)(ws + oUL);
    short* TAP = (short*)(ws + oTAP);
    int*   HDR = (int*)(ws + oHDR);
    float* INVN = (float*)(ws + oINVN);
    unsigned short* BGTc4 = (unsigned short*)(ws + oBGTC);
    unsigned short* Pc4   = (unsigned short*)(ws + oPC);
    unsigned short* fpad4 = (unsigned short*)(ws + oFPAD);
    unsigned short* bpad4 = (unsigned short*)(ws + oBPAD);
    unsigned short* Scc4 = (unsigned short*)(ws + oSCC);
    unsigned short* OUTT4 = (unsigned short*)(ws + oSCC);  // Scc dead after fuse
    float* SSQ = (float*)(ws + oSCC);    // 9-tap Q sums; dead before gemm1 writes Scc

    dst_kernel<<<dim3(64, 4, 8), 256, 0, stream>>>(f, b, fpad4, bpad4);
    qk_border_kernel<<<dim3(1297, 4), 256, 0, stream>>>(fpad4, bpad4, Q);
    ss_kernel<<<dim3(16, 4), 256, 0, stream>>>(Q, SSQ);
    compact_kernel<<<4, 1024, 0, stream>>>(mask, SSQ, ACT, UL, TAP, INVN, HDR);
    prep_bgtc_kernel<<<dim3(2304, 4), 256, 0, stream>>>(b, ACT, HDR, BGTc4);

    gemm1_8phase<<<dim3(128, 4), 512, 0, stream>>>(fpad4, bpad4, Scc4, UL, HDR, INVN);
    fuse_softmax_kernel<<<dim3(512, 4), 512, 0, stream>>>(Scc4, HDR, TAP, Pc4);

    gemm2_nt<<<dim3(32, 9, 4), 256, 0, stream>>>(BGTc4, Pc4, HDR, OUTT4);
    scatter_kernel<<<dim3(8192, 4), 256, 0, stream>>>(OUTT4, out);
    (void)in_sizes; (void)n_in; (void)out_size; (void)ws_size;
}